// Round 1
// baseline (4957.987 us; speedup 1.0000x reference)
//
#include <hip/hip_runtime.h>
#include <hip/hip_bf16.h>
#include <math.h>

#define NN 50000
#define EE 800000
#define HH 8
#define DD 16
#define HDIM 128
#define LL 6
#define GG 64
#define NDI 48
#define EDI 4
#define FFD 512

// ---------------- node input projection: x = h @ node_W + node_b ----------------
__global__ void k_node_proj(const float* __restrict__ h, const float* __restrict__ W,
                            const float* __restrict__ b, float* __restrict__ x) {
  __shared__ float hs[32][NDI];
  int t = threadIdx.x;                 // 128
  int n0 = blockIdx.x * 32;
  for (int idx = t; idx < 32 * NDI; idx += 128) {
    int nb = idx / NDI, i = idx - nb * NDI;
    int node = n0 + nb;
    hs[nb][i] = (node < NN) ? h[node * NDI + i] : 0.f;
  }
  __syncthreads();
  float acc[32];
#pragma unroll
  for (int nb = 0; nb < 32; nb++) acc[nb] = 0.f;
  for (int i = 0; i < NDI; i++) {
    float w = W[i * HDIM + t];
#pragma unroll
    for (int nb = 0; nb < 32; nb++) acc[nb] += hs[nb][i] * w;
  }
  float bb = b[t];
  for (int nb = 0; nb < 32; nb++) {
    int node = n0 + nb;
    if (node < NN) x[node * HDIM + t] = acc[nb] + bb;
  }
}

// ------- combined edge-bias matrices: Wcomb[l] = edge_W @ Web[l]  [4x8], bcomb -------
__global__ void k_wcomb(const float* __restrict__ edge_W, const float* __restrict__ edge_b,
                        const float* __restrict__ Web, const float* __restrict__ beb,
                        float* __restrict__ Wcomb, float* __restrict__ bcomb) {
  int t = threadIdx.x;  // 256
  if (t < LL * EDI * HH) {  // 192
    int l = t / (EDI * HH);
    int i = (t / HH) % EDI;
    int hh = t % HH;
    float s = 0.f;
    for (int j = 0; j < HDIM; j++) s += edge_W[i * HDIM + j] * Web[(l * HDIM + j) * HH + hh];
    Wcomb[t] = s;
  } else if (t < LL * EDI * HH + LL * HH) {  // next 48
    int u = t - LL * EDI * HH;
    int l = u / HH, hh = u % HH;
    float s = beb[l * HH + hh];
    for (int j = 0; j < HDIM; j++) s += edge_b[j] * Web[(l * HDIM + j) * HH + hh];
    bcomb[u] = s;
  }
}

// ---------------- CSR build ----------------
__global__ void k_deg(const int* __restrict__ row, int* __restrict__ deg) {
  int e = blockIdx.x * 256 + threadIdx.x;
  if (e < EE) atomicAdd(&deg[row[e]], 1);
}

__global__ void k_scan(const int* __restrict__ deg, int* __restrict__ starts,
                       int* __restrict__ cursor, int n) {
  __shared__ int sdata[1024];
  __shared__ int s_running;
  int tid = threadIdx.x;
  if (tid == 0) s_running = 0;
  __syncthreads();
  for (int base = 0; base < n; base += 1024) {
    int i = base + tid;
    int v = (i < n) ? deg[i] : 0;
    sdata[tid] = v;
    __syncthreads();
    for (int off = 1; off < 1024; off <<= 1) {
      int tv = (tid >= off) ? sdata[tid - off] : 0;
      __syncthreads();
      sdata[tid] += tv;
      __syncthreads();
    }
    int excl = sdata[tid] - v;
    int total = sdata[1023];
    int sval = s_running + excl;
    if (i < n) { starts[i] = sval; cursor[i] = sval; }
    __syncthreads();
    if (tid == 0) s_running += total;
    __syncthreads();
  }
  if (tid == 0) starts[n] = s_running;
}

__global__ void k_scatter(const int* __restrict__ row, int* __restrict__ cursor,
                          int* __restrict__ eids) {
  int e = blockIdx.x * 256 + threadIdx.x;
  if (e < EE) {
    int r = row[e];
    int pos = atomicAdd(&cursor[r], 1);
    eids[pos] = e;
  }
}

__global__ void k_gcnt(const int* __restrict__ batch, int* __restrict__ gcnt) {
  int i = blockIdx.x * 256 + threadIdx.x;
  if (i < NN) atomicAdd(&gcnt[batch[i]], 1);
}

__global__ void k_bscan(const int* __restrict__ gcnt, int* __restrict__ gstart) {
  if (threadIdx.x == 0) {
    int s = 0;
    for (int g = 0; g < GG; g++) { gstart[g] = s; s += gcnt[g]; }
    gstart[GG] = s;
  }
}

// ---------------- LN1 + QKV projection ----------------
__global__ void k_ln_qkv(const float* __restrict__ x,
                         const float* __restrict__ Wq, const float* __restrict__ bq,
                         const float* __restrict__ Wk, const float* __restrict__ bk,
                         const float* __restrict__ Wv, const float* __restrict__ bv,
                         const float* __restrict__ g, const float* __restrict__ be,
                         float* __restrict__ q, float* __restrict__ k, float* __restrict__ v) {
  __shared__ float xs[16][HDIM + 1];
  __shared__ float mv[16][2];
  int t = threadIdx.x;  // 128
  int n0 = blockIdx.x * 16;
  for (int nb = 0; nb < 16; nb++) {
    int node = n0 + nb;
    xs[nb][t] = (node < NN) ? x[node * HDIM + t] : 0.f;
  }
  __syncthreads();
  if (t < 16) {
    float m = 0.f;
    for (int i = 0; i < HDIM; i++) m += xs[t][i];
    m *= (1.f / HDIM);
    float var = 0.f;
    for (int i = 0; i < HDIM; i++) { float d = xs[t][i] - m; var += d * d; }
    var *= (1.f / HDIM);
    mv[t][0] = m;
    mv[t][1] = rsqrtf(var + 1e-5f);
  }
  __syncthreads();
  float gg = g[t], bb = be[t];
  for (int nb = 0; nb < 16; nb++) xs[nb][t] = (xs[nb][t] - mv[nb][0]) * mv[nb][1] * gg + bb;
  __syncthreads();

  float acc[16];
  // Q
#pragma unroll
  for (int nb = 0; nb < 16; nb++) acc[nb] = 0.f;
  for (int i = 0; i < HDIM; i++) {
    float w = Wq[i * HDIM + t];
#pragma unroll
    for (int nb = 0; nb < 16; nb++) acc[nb] += xs[nb][i] * w;
  }
  {
    float b0 = bq[t];
    for (int nb = 0; nb < 16; nb++) { int node = n0 + nb; if (node < NN) q[node * HDIM + t] = acc[nb] + b0; }
  }
  // K
#pragma unroll
  for (int nb = 0; nb < 16; nb++) acc[nb] = 0.f;
  for (int i = 0; i < HDIM; i++) {
    float w = Wk[i * HDIM + t];
#pragma unroll
    for (int nb = 0; nb < 16; nb++) acc[nb] += xs[nb][i] * w;
  }
  {
    float b0 = bk[t];
    for (int nb = 0; nb < 16; nb++) { int node = n0 + nb; if (node < NN) k[node * HDIM + t] = acc[nb] + b0; }
  }
  // V
#pragma unroll
  for (int nb = 0; nb < 16; nb++) acc[nb] = 0.f;
  for (int i = 0; i < HDIM; i++) {
    float w = Wv[i * HDIM + t];
#pragma unroll
    for (int nb = 0; nb < 16; nb++) acc[nb] += xs[nb][i] * w;
  }
  {
    float b0 = bv[t];
    for (int nb = 0; nb < 16; nb++) { int node = n0 + nb; if (node < NN) v[node * HDIM + t] = acc[nb] + b0; }
  }
}

// ---------------- attention: per-node over CSR edge list ----------------
__global__ void k_attn(const float* __restrict__ q, const float* __restrict__ k,
                       const float* __restrict__ v, const float* __restrict__ efeat,
                       const int* __restrict__ colArr, const int* __restrict__ eids,
                       const int* __restrict__ starts,
                       const float* __restrict__ Wcomb, const float* __restrict__ bcomb,
                       float* __restrict__ out) {
  int node = blockIdx.x;
  int t = threadIdx.x;  // 128
  __shared__ float qs[HDIM];
  __shared__ float exbuf[8][HH];
  __shared__ int cbuf[8];
  __shared__ float wc[EDI * HH];
  __shared__ float bc[HH];
  qs[t] = q[node * HDIM + t];
  if (t < EDI * HH) wc[t] = Wcomb[t];
  if (t < HH) bc[t] = bcomb[t];
  __syncthreads();
  int s0 = starts[node], s1 = starts[node + 1];
  int h_acc = t >> 4;   // phase-2 mapping
  int jsub = t >> 4;    // phase-1 mapping: edge in chunk
  int d = t & 15;
  float acc = 0.f;
  float lsum = 0.f;
  for (int base = s0; base < s1; base += 8) {
    int nj = min(8, s1 - base);
    if (jsub < nj) {
      int e = eids[base + jsub];
      int c = colArr[e];
      if (d == 0) cbuf[jsub] = c;
      const float* kr = k + (size_t)c * HDIM;
      const float* ef = efeat + (size_t)e * EDI;
      float e0 = ef[0], e1 = ef[1], e2 = ef[2], e3 = ef[3];
#pragma unroll
      for (int hh = 0; hh < HH; hh++) {
        float part = qs[hh * 16 + d] * kr[hh * 16 + d];
        part += __shfl_xor(part, 1);
        part += __shfl_xor(part, 2);
        part += __shfl_xor(part, 4);
        part += __shfl_xor(part, 8);
        if (d == 0) {
          float eb = bc[hh] + e0 * wc[0 * HH + hh] + e1 * wc[1 * HH + hh] +
                     e2 * wc[2 * HH + hh] + e3 * wc[3 * HH + hh];
          exbuf[jsub][hh] = __expf(part * 0.25f + eb);
        }
      }
    }
    __syncthreads();
    for (int jj = 0; jj < nj; jj++) {
      float ex = exbuf[jj][h_acc];
      lsum += ex;
      acc += ex * v[(size_t)cbuf[jj] * HDIM + t];
    }
    __syncthreads();
  }
  out[node * HDIM + t] = acc / (lsum + 1e-10f);
}

// ---------------- out-projection + residual: x = ao @ Wo + bo + x ----------------
__global__ void k_oproj(const float* __restrict__ ao, const float* __restrict__ Wo,
                        const float* __restrict__ bo, float* __restrict__ x) {
  __shared__ float as[16][HDIM];
  int t = threadIdx.x;  // 128
  int n0 = blockIdx.x * 16;
  for (int nb = 0; nb < 16; nb++) {
    int node = n0 + nb;
    as[nb][t] = (node < NN) ? ao[node * HDIM + t] : 0.f;
  }
  __syncthreads();
  float acc[16];
#pragma unroll
  for (int nb = 0; nb < 16; nb++) acc[nb] = 0.f;
  for (int i = 0; i < HDIM; i++) {
    float w = Wo[i * HDIM + t];
#pragma unroll
    for (int nb = 0; nb < 16; nb++) acc[nb] += as[nb][i] * w;
  }
  float bb = bo[t];
  for (int nb = 0; nb < 16; nb++) {
    int node = n0 + nb;
    if (node < NN) x[node * HDIM + t] = acc[nb] + bb + x[node * HDIM + t];
  }
}

// ---------------- LN2 + FFN + residual (in-place on x) ----------------
__global__ void k_ffn(const float* __restrict__ xin,
                      const float* __restrict__ W1, const float* __restrict__ b1,
                      const float* __restrict__ W2, const float* __restrict__ b2,
                      const float* __restrict__ g, const float* __restrict__ be,
                      float* __restrict__ x) {
  __shared__ float xs[16][HDIM + 1];
  __shared__ float hs[16][FFD];
  __shared__ float mv[16][2];
  int t = threadIdx.x;  // 256
  int n0 = blockIdx.x * 16;
  for (int idx = t; idx < 16 * HDIM; idx += 256) {
    int nb = idx >> 7, i = idx & 127;
    int node = n0 + nb;
    xs[nb][i] = (node < NN) ? xin[node * HDIM + i] : 0.f;
  }
  __syncthreads();
  if (t < 16) {
    float m = 0.f;
    for (int i = 0; i < HDIM; i++) m += xs[t][i];
    m *= (1.f / HDIM);
    float var = 0.f;
    for (int i = 0; i < HDIM; i++) { float dv = xs[t][i] - m; var += dv * dv; }
    var *= (1.f / HDIM);
    mv[t][0] = m;
    mv[t][1] = rsqrtf(var + 1e-5f);
  }
  __syncthreads();
  for (int idx = t; idx < 16 * HDIM; idx += 256) {
    int nb = idx >> 7, i = idx & 127;
    xs[nb][i] = (xs[nb][i] - mv[nb][0]) * mv[nb][1] * g[i] + be[i];
  }
  __syncthreads();
  // hidden layer: thread t handles columns t and t+256
  float a0[16], a1[16];
#pragma unroll
  for (int nb = 0; nb < 16; nb++) { a0[nb] = 0.f; a1[nb] = 0.f; }
  for (int i = 0; i < HDIM; i++) {
    float w0 = W1[i * FFD + t];
    float w1 = W1[i * FFD + t + 256];
#pragma unroll
    for (int nb = 0; nb < 16; nb++) {
      float xv = xs[nb][i];
      a0[nb] += xv * w0;
      a1[nb] += xv * w1;
    }
  }
  {
    float bb0 = b1[t], bb1 = b1[t + 256];
    for (int nb = 0; nb < 16; nb++) {
      hs[nb][t] = fmaxf(a0[nb] + bb0, 0.f);
      hs[nb][t + 256] = fmaxf(a1[nb] + bb1, 0.f);
    }
  }
  __syncthreads();
  // output layer: (oc = t&127, half = t>>7), each sums 256 of the 512 hidden
  float o[16];
#pragma unroll
  for (int nb = 0; nb < 16; nb++) o[nb] = 0.f;
  int oc = t & 127, half = t >> 7;
  int i0 = half * 256;
  for (int i = i0; i < i0 + 256; i++) {
    float w = W2[i * HDIM + oc];
#pragma unroll
    for (int nb = 0; nb < 16; nb++) o[nb] += hs[nb][i] * w;
  }
  __syncthreads();  // xs reads all done; reuse xs as partial buffer
  if (half == 1) {
    for (int nb = 0; nb < 16; nb++) xs[nb][oc] = o[nb];
  }
  __syncthreads();
  if (half == 0) {
    float bb = b2[oc];
    for (int nb = 0; nb < 16; nb++) {
      int node = n0 + nb;
      if (node < NN) {
        float res = xin[node * HDIM + oc];
        x[node * HDIM + oc] = o[nb] + xs[nb][oc] + bb + res;
      }
    }
  }
}

// ---------------- final LN -> d_out ----------------
__global__ void k_final(const float* __restrict__ x, const float* __restrict__ g,
                        const float* __restrict__ be, float* __restrict__ outx) {
  __shared__ float xs[16][HDIM + 1];
  __shared__ float mv[16][2];
  int t = threadIdx.x;  // 128
  int n0 = blockIdx.x * 16;
  for (int nb = 0; nb < 16; nb++) {
    int node = n0 + nb;
    xs[nb][t] = (node < NN) ? x[node * HDIM + t] : 0.f;
  }
  __syncthreads();
  if (t < 16) {
    float m = 0.f;
    for (int i = 0; i < HDIM; i++) m += xs[t][i];
    m *= (1.f / HDIM);
    float var = 0.f;
    for (int i = 0; i < HDIM; i++) { float d = xs[t][i] - m; var += d * d; }
    var *= (1.f / HDIM);
    mv[t][0] = m;
    mv[t][1] = rsqrtf(var + 1e-5f);
  }
  __syncthreads();
  float gg = g[t], bb = be[t];
  for (int nb = 0; nb < 16; nb++) {
    int node = n0 + nb;
    if (node < NN) outx[node * HDIM + t] = (xs[nb][t] - mv[nb][0]) * mv[nb][1] * gg + bb;
  }
}

// ---------------- graph mean pooling (batch is sorted) ----------------
__global__ void k_pool(const float* __restrict__ outx, const int* __restrict__ gstart,
                       const int* __restrict__ gcnt, float* __restrict__ outg) {
  __shared__ float part[4][HDIM];
  int g = blockIdx.x;
  int t = threadIdx.x;  // 512
  int hd = t & 127, p = t >> 7;
  int s0 = gstart[g];
  int c = gcnt[g];
  float s = 0.f;
  for (int i = p; i < c; i += 4) s += outx[(size_t)(s0 + i) * HDIM + hd];
  part[p][hd] = s;
  __syncthreads();
  if (p == 0) {
    float tot = part[0][hd] + part[1][hd] + part[2][hd] + part[3][hd];
    outg[g * HDIM + hd] = tot / fmaxf((float)c, 1.f);
  }
}

extern "C" void kernel_launch(void* const* d_in, const int* in_sizes, int n_in,
                              void* d_out, int out_size, void* d_ws, size_t ws_size,
                              hipStream_t stream) {
  const float* h      = (const float*)d_in[0];
  const float* e      = (const float*)d_in[1];
  const int*   eidx   = (const int*)d_in[2];
  const int*   batch  = (const int*)d_in[3];
  const float* node_W = (const float*)d_in[4];
  const float* node_b = (const float*)d_in[5];
  const float* edge_W = (const float*)d_in[6];
  const float* edge_b = (const float*)d_in[7];
  const float* Wq  = (const float*)d_in[8];
  const float* bq  = (const float*)d_in[9];
  const float* Wk  = (const float*)d_in[10];
  const float* bk  = (const float*)d_in[11];
  const float* Wv  = (const float*)d_in[12];
  const float* bv  = (const float*)d_in[13];
  const float* Wo  = (const float*)d_in[14];
  const float* bo  = (const float*)d_in[15];
  const float* Web = (const float*)d_in[16];
  const float* beb = (const float*)d_in[17];
  const float* W1  = (const float*)d_in[18];
  const float* b1  = (const float*)d_in[19];
  const float* W2  = (const float*)d_in[20];
  const float* b2  = (const float*)d_in[21];
  const float* g1  = (const float*)d_in[22];
  const float* be1 = (const float*)d_in[23];
  const float* g2  = (const float*)d_in[24];
  const float* be2 = (const float*)d_in[25];
  const float* gF  = (const float*)d_in[26];
  const float* bF  = (const float*)d_in[27];

  const int* rowArr = eidx;
  const int* colArr = eidx + EE;

  char* ws = (char*)d_ws;
  size_t off = 0;
  auto alloc = [&](size_t bytes) -> void* {
    void* p = ws + off;
    off = (off + bytes + 255) & ~(size_t)255;
    return p;
  };
  float* x    = (float*)alloc((size_t)NN * HDIM * 4);
  float* qb   = (float*)alloc((size_t)NN * HDIM * 4);
  float* kb   = (float*)alloc((size_t)NN * HDIM * 4);
  float* vb   = (float*)alloc((size_t)NN * HDIM * 4);
  float* ao   = (float*)alloc((size_t)NN * HDIM * 4);
  int* deg    = (int*)alloc((size_t)NN * 4);
  int* starts = (int*)alloc((size_t)(NN + 1) * 4);
  int* cursor = (int*)alloc((size_t)NN * 4);
  int* eids   = (int*)alloc((size_t)EE * 4);
  float* Wcomb = (float*)alloc((size_t)LL * EDI * HH * 4);
  float* bcomb = (float*)alloc((size_t)LL * HH * 4);
  int* gcnt   = (int*)alloc((size_t)GG * 4);
  int* gstart = (int*)alloc((size_t)(GG + 1) * 4);

  hipMemsetAsync(deg, 0, (size_t)NN * 4, stream);
  hipMemsetAsync(gcnt, 0, (size_t)GG * 4, stream);

  k_node_proj<<<(NN + 31) / 32, 128, 0, stream>>>(h, node_W, node_b, x);
  k_wcomb<<<1, 256, 0, stream>>>(edge_W, edge_b, Web, beb, Wcomb, bcomb);
  k_deg<<<(EE + 255) / 256, 256, 0, stream>>>(rowArr, deg);
  k_scan<<<1, 1024, 0, stream>>>(deg, starts, cursor, NN);
  k_scatter<<<(EE + 255) / 256, 256, 0, stream>>>(rowArr, cursor, eids);
  k_gcnt<<<(NN + 255) / 256, 256, 0, stream>>>(batch, gcnt);
  k_bscan<<<1, 64, 0, stream>>>(gcnt, gstart);

  int nblk16 = (NN + 15) / 16;
  for (int l = 0; l < LL; l++) {
    k_ln_qkv<<<nblk16, 128, 0, stream>>>(x,
        Wq + (size_t)l * HDIM * HDIM, bq + (size_t)l * HDIM,
        Wk + (size_t)l * HDIM * HDIM, bk + (size_t)l * HDIM,
        Wv + (size_t)l * HDIM * HDIM, bv + (size_t)l * HDIM,
        g1 + (size_t)l * HDIM, be1 + (size_t)l * HDIM, qb, kb, vb);
    k_attn<<<NN, 128, 0, stream>>>(qb, kb, vb, e, colArr, eids, starts,
        Wcomb + (size_t)l * EDI * HH, bcomb + (size_t)l * HH, ao);
    k_oproj<<<nblk16, 128, 0, stream>>>(ao, Wo + (size_t)l * HDIM * HDIM,
        bo + (size_t)l * HDIM, x);
    k_ffn<<<nblk16, 256, 0, stream>>>(x,
        W1 + (size_t)l * HDIM * FFD, b1 + (size_t)l * FFD,
        W2 + (size_t)l * FFD * HDIM, b2 + (size_t)l * HDIM,
        g2 + (size_t)l * HDIM, be2 + (size_t)l * HDIM, x);
  }

  float* outx = (float*)d_out;
  float* outg = outx + (size_t)NN * HDIM;
  k_final<<<nblk16, 128, 0, stream>>>(x, gF, bF, outx);
  k_pool<<<GG, 512, 0, stream>>>(outx, gstart, gcnt, outg);
}

// Round 2
// 2604.790 us; speedup vs baseline: 1.9034x; 1.9034x over previous
//
#include <hip/hip_runtime.h>
#include <hip/hip_bf16.h>
#include <math.h>

#define NN 50000
#define EE 800000
#define HH 8
#define DD 16
#define HDIM 128
#define LL 6
#define GG 64
#define NDI 48
#define EDI 4
#define FFD 512

typedef __attribute__((ext_vector_type(8))) short short8;
typedef __attribute__((ext_vector_type(8))) unsigned short ushort8;
typedef __attribute__((ext_vector_type(4))) float floatx4;

__device__ __forceinline__ unsigned short f2bf(float f) {
  unsigned u = __builtin_bit_cast(unsigned, f);
  unsigned rnd = 0x7FFFu + ((u >> 16) & 1u);
  return (unsigned short)((u + rnd) >> 16);
}
__device__ __forceinline__ float bf2f(unsigned short u) {
  unsigned v = ((unsigned)u) << 16;
  return __builtin_bit_cast(float, v);
}

// ---------------- node input projection: x = h @ node_W + node_b (fp32) ----------------
__global__ void k_node_proj(const float* __restrict__ h, const float* __restrict__ W,
                            const float* __restrict__ b, float* __restrict__ x) {
  __shared__ float hs[32][NDI];
  int t = threadIdx.x;                 // 128
  int n0 = blockIdx.x * 32;
  for (int idx = t; idx < 32 * NDI; idx += 128) {
    int nb = idx / NDI, i = idx - nb * NDI;
    int node = n0 + nb;
    hs[nb][i] = (node < NN) ? h[node * NDI + i] : 0.f;
  }
  __syncthreads();
  float acc[32];
#pragma unroll
  for (int nb = 0; nb < 32; nb++) acc[nb] = 0.f;
  for (int i = 0; i < NDI; i++) {
    float w = W[i * HDIM + t];
#pragma unroll
    for (int nb = 0; nb < 32; nb++) acc[nb] += hs[nb][i] * w;
  }
  float bb = b[t];
  for (int nb = 0; nb < 32; nb++) {
    int node = n0 + nb;
    if (node < NN) x[node * HDIM + t] = acc[nb] + bb;
  }
}

// ------- weight fragment pre-pack: W[m][K][OC] fp32 -> [m][OC/16][K/32][64][8] bf16 -------
__global__ void k_pack(const float* __restrict__ W, unsigned short* __restrict__ dst,
                       int K, int OC, int nmat) {
  int KC = K >> 5, CT = OC >> 4;
  int total = nmat * CT * KC * 512;
  for (int i = blockIdx.x * 256 + threadIdx.x; i < total; i += gridDim.x * 256) {
    int j = i & 7;
    int lane = (i >> 3) & 63;
    int rest = i >> 9;
    int kc = rest % KC; rest /= KC;
    int ct = rest % CT; int m = rest / CT;
    int col = ct * 16 + (lane & 15);
    int k = kc * 32 + (lane >> 4) * 8 + j;
    dst[i] = f2bf(W[(size_t)m * K * OC + (size_t)k * OC + col]);
  }
}

// ------- combined edge-bias matrices: Wcomb[l] = edge_W @ Web[l]  [4x8], bcomb -------
__global__ void k_wcomb(const float* __restrict__ edge_W, const float* __restrict__ edge_b,
                        const float* __restrict__ Web, const float* __restrict__ beb,
                        float* __restrict__ Wcomb, float* __restrict__ bcomb) {
  int t = threadIdx.x;  // 256
  if (t < LL * EDI * HH) {  // 192
    int l = t / (EDI * HH);
    int i = (t / HH) % EDI;
    int hh = t % HH;
    float s = 0.f;
    for (int j = 0; j < HDIM; j++) s += edge_W[i * HDIM + j] * Web[(l * HDIM + j) * HH + hh];
    Wcomb[t] = s;
  } else if (t < LL * EDI * HH + LL * HH) {  // next 48
    int u = t - LL * EDI * HH;
    int l = u / HH, hh = u % HH;
    float s = beb[l * HH + hh];
    for (int j = 0; j < HDIM; j++) s += edge_b[j] * Web[(l * HDIM + j) * HH + hh];
    bcomb[u] = s;
  }
}

// ---------------- CSR build ----------------
__global__ void k_deg(const int* __restrict__ row, int* __restrict__ deg) {
  int e = blockIdx.x * 256 + threadIdx.x;
  if (e < EE) atomicAdd(&deg[row[e]], 1);
}

__global__ void k_scan(const int* __restrict__ deg, int* __restrict__ starts,
                       int* __restrict__ cursor, int n) {
  __shared__ int sdata[1024];
  __shared__ int s_running;
  int tid = threadIdx.x;
  if (tid == 0) s_running = 0;
  __syncthreads();
  for (int base = 0; base < n; base += 1024) {
    int i = base + tid;
    int v = (i < n) ? deg[i] : 0;
    sdata[tid] = v;
    __syncthreads();
    for (int off = 1; off < 1024; off <<= 1) {
      int tv = (tid >= off) ? sdata[tid - off] : 0;
      __syncthreads();
      sdata[tid] += tv;
      __syncthreads();
    }
    int excl = sdata[tid] - v;
    int total = sdata[1023];
    int sval = s_running + excl;
    if (i < n) { starts[i] = sval; cursor[i] = sval; }
    __syncthreads();
    if (tid == 0) s_running += total;
    __syncthreads();
  }
  if (tid == 0) starts[n] = s_running;
}

__global__ void k_scatter(const int* __restrict__ row, int* __restrict__ cursor,
                          int* __restrict__ eids) {
  int e = blockIdx.x * 256 + threadIdx.x;
  if (e < EE) {
    int r = row[e];
    int pos = atomicAdd(&cursor[r], 1);
    eids[pos] = e;
  }
}

__global__ void k_gcnt(const int* __restrict__ batch, int* __restrict__ gcnt) {
  int i = blockIdx.x * 256 + threadIdx.x;
  if (i < NN) atomicAdd(&gcnt[batch[i]], 1);
}

__global__ void k_bscan(const int* __restrict__ gcnt, int* __restrict__ gstart) {
  if (threadIdx.x == 0) {
    int s = 0;
    for (int g = 0; g < GG; g++) { gstart[g] = s; s += gcnt[g]; }
    gstart[GG] = s;
  }
}

// ---------------- LN1 + QKV projection via MFMA: 64 nodes/block, 4 waves ----------------
__global__ __launch_bounds__(256) void k_ln_qkv_mfma(
    const float* __restrict__ x,
    const unsigned short* __restrict__ Wqf, const float* __restrict__ bq,
    const unsigned short* __restrict__ Wkf, const float* __restrict__ bk,
    const unsigned short* __restrict__ Wvf, const float* __restrict__ bv,
    const float* __restrict__ g, const float* __restrict__ be,
    unsigned short* __restrict__ q, unsigned short* __restrict__ k,
    unsigned short* __restrict__ v) {
  __shared__ unsigned short xn[64][136];
  int t = threadIdx.x;
  int n0 = blockIdx.x * 64;
  {
    int row = t >> 2, quad = t & 3;   // 4 lanes/row, 32 elems each
    int node = n0 + row;
    float xv[32];
    float s = 0.f, sq = 0.f;
    if (node < NN) {
      const float* xr = x + (size_t)node * HDIM + quad * 32;
#pragma unroll
      for (int c = 0; c < 8; c++) {
        float4 f = *(const float4*)(xr + c * 4);
        xv[c*4+0]=f.x; xv[c*4+1]=f.y; xv[c*4+2]=f.z; xv[c*4+3]=f.w;
      }
#pragma unroll
      for (int j = 0; j < 32; j++) { s += xv[j]; sq += xv[j]*xv[j]; }
    } else {
#pragma unroll
      for (int j = 0; j < 32; j++) xv[j] = 0.f;
    }
    s += __shfl_xor(s, 1); s += __shfl_xor(s, 2);
    sq += __shfl_xor(sq, 1); sq += __shfl_xor(sq, 2);
    float m = s * (1.f / HDIM);
    float rv = rsqrtf(sq * (1.f / HDIM) - m * m + 1e-5f);
#pragma unroll
    for (int cb = 0; cb < 4; cb++) {
      ushort8 u;
#pragma unroll
      for (int j = 0; j < 8; j++) {
        int col = quad * 32 + cb * 8 + j;
        u[j] = f2bf((xv[cb*8+j] - m) * rv * g[col] + be[col]);
      }
      *(ushort8*)&xn[row][quad * 32 + cb * 8] = u;
    }
  }
  __syncthreads();
  int w = t >> 6, lane = t & 63;
  int r0 = w * 16;
  short8 a[4];
#pragma unroll
  for (int kc = 0; kc < 4; kc++)
    a[kc] = *(const short8*)&xn[r0 + (lane & 15)][kc * 32 + (lane >> 4) * 8];
  const unsigned short* Wf[3] = {Wqf, Wkf, Wvf};
  const float* bias[3] = {bq, bk, bv};
  unsigned short* outp[3] = {q, k, v};
#pragma unroll
  for (int mm = 0; mm < 3; mm++) {
    const unsigned short* wf = Wf[mm];
    for (int ct = 0; ct < 8; ct++) {
      floatx4 acc = {0.f, 0.f, 0.f, 0.f};
#pragma unroll
      for (int kc = 0; kc < 4; kc++) {
        short8 b = *(const short8*)(wf + ((size_t)(ct * 4 + kc) * 64 + lane) * 8);
        acc = __builtin_amdgcn_mfma_f32_16x16x32_bf16(a[kc], b, acc, 0, 0, 0);
      }
      int col = ct * 16 + (lane & 15);
      float bb = bias[mm][col];
#pragma unroll
      for (int r = 0; r < 4; r++) {
        int rr = r0 + (lane >> 4) * 4 + r;
        int nd = n0 + rr;
        if (nd < NN) outp[mm][(size_t)nd * HDIM + col] = f2bf(acc[r] + bb);
      }
    }
  }
}

// ---------------- attention: per-node over CSR edge list (bf16 q/k/v) ----------------
__global__ void k_attn(const unsigned short* __restrict__ q, const unsigned short* __restrict__ k,
                       const unsigned short* __restrict__ v, const float* __restrict__ efeat,
                       const int* __restrict__ colArr, const int* __restrict__ eids,
                       const int* __restrict__ starts,
                       const float* __restrict__ Wcomb, const float* __restrict__ bcomb,
                       unsigned short* __restrict__ out) {
  int node = blockIdx.x;
  int t = threadIdx.x;  // 128
  __shared__ float qs[HDIM];
  __shared__ float exbuf[8][HH];
  __shared__ int cbuf[8];
  __shared__ float wc[EDI * HH];
  __shared__ float bc[HH];
  qs[t] = bf2f(q[(size_t)node * HDIM + t]);
  if (t < EDI * HH) wc[t] = Wcomb[t];
  if (t < HH) bc[t] = bcomb[t];
  __syncthreads();
  int s0 = starts[node], s1 = starts[node + 1];
  int h_acc = t >> 4;
  int jsub = t >> 4;
  int d = t & 15;
  float acc = 0.f;
  float lsum = 0.f;
  for (int base = s0; base < s1; base += 8) {
    int nj = min(8, s1 - base);
    if (jsub < nj) {
      int e = eids[base + jsub];
      int c = colArr[e];
      if (d == 0) cbuf[jsub] = c;
      const unsigned short* kr = k + (size_t)c * HDIM;
      const float* ef = efeat + (size_t)e * EDI;
      float e0 = ef[0], e1 = ef[1], e2 = ef[2], e3 = ef[3];
#pragma unroll
      for (int hh = 0; hh < HH; hh++) {
        float part = qs[hh * 16 + d] * bf2f(kr[hh * 16 + d]);
        part += __shfl_xor(part, 1);
        part += __shfl_xor(part, 2);
        part += __shfl_xor(part, 4);
        part += __shfl_xor(part, 8);
        if (d == 0) {
          float eb = bc[hh] + e0 * wc[0 * HH + hh] + e1 * wc[1 * HH + hh] +
                     e2 * wc[2 * HH + hh] + e3 * wc[3 * HH + hh];
          exbuf[jsub][hh] = __expf(part * 0.25f + eb);
        }
      }
    }
    __syncthreads();
    for (int jj = 0; jj < nj; jj++) {
      float ex = exbuf[jj][h_acc];
      lsum += ex;
      acc += ex * bf2f(v[(size_t)cbuf[jj] * HDIM + t]);
    }
    __syncthreads();
  }
  out[(size_t)node * HDIM + t] = f2bf(acc / (lsum + 1e-10f));
}

// ---------------- out-projection + residual via MFMA ----------------
__global__ __launch_bounds__(256) void k_oproj_mfma(
    const unsigned short* __restrict__ ao, const unsigned short* __restrict__ Wof,
    const float* __restrict__ bo, float* __restrict__ x) {
  __shared__ unsigned short aos[64][136];
  int t = threadIdx.x;
  int n0 = blockIdx.x * 64;
#pragma unroll
  for (int c = 0; c < 4; c++) {
    int elem = c * 2048 + t * 8;
    int row = elem >> 7, col = elem & 127;
    int nd = n0 + row;
    ushort8 u = {0, 0, 0, 0, 0, 0, 0, 0};
    if (nd < NN) u = *(const ushort8*)(ao + (size_t)nd * HDIM + col);
    *(ushort8*)&aos[row][col] = u;
  }
  __syncthreads();
  int w = t >> 6, lane = t & 63;
  int r0 = w * 16;
  short8 a[4];
#pragma unroll
  for (int kc = 0; kc < 4; kc++)
    a[kc] = *(const short8*)&aos[r0 + (lane & 15)][kc * 32 + (lane >> 4) * 8];
  for (int ct = 0; ct < 8; ct++) {
    floatx4 acc = {0.f, 0.f, 0.f, 0.f};
#pragma unroll
    for (int kc = 0; kc < 4; kc++) {
      short8 b = *(const short8*)(Wof + ((size_t)(ct * 4 + kc) * 64 + lane) * 8);
      acc = __builtin_amdgcn_mfma_f32_16x16x32_bf16(a[kc], b, acc, 0, 0, 0);
    }
    int col = ct * 16 + (lane & 15);
    float bb = bo[col];
#pragma unroll
    for (int r = 0; r < 4; r++) {
      int rr = r0 + (lane >> 4) * 4 + r;
      int nd = n0 + rr;
      if (nd < NN) {
        size_t idx = (size_t)nd * HDIM + col;
        x[idx] = x[idx] + acc[r] + bb;
      }
    }
  }
}

// ---------------- LN2 + FFN + residual via MFMA: 32 nodes/block ----------------
__global__ __launch_bounds__(256) void k_ffn_mfma(
    const float* __restrict__ xin,
    const unsigned short* __restrict__ W1f, const float* __restrict__ b1,
    const unsigned short* __restrict__ W2f, const float* __restrict__ b2,
    const float* __restrict__ g, const float* __restrict__ be,
    float* __restrict__ x) {
  __shared__ unsigned short xn[32][136];
  __shared__ unsigned short hs[32][520];
  int t = threadIdx.x;
  int n0 = blockIdx.x * 32;
  {
    int row = t >> 3, oct = t & 7;   // 8 lanes/row, 16 elems each
    int node = n0 + row;
    float xv[16];
    float s = 0.f, sq = 0.f;
    if (node < NN) {
      const float* xr = xin + (size_t)node * HDIM + oct * 16;
#pragma unroll
      for (int c = 0; c < 4; c++) {
        float4 f = *(const float4*)(xr + c * 4);
        xv[c*4+0]=f.x; xv[c*4+1]=f.y; xv[c*4+2]=f.z; xv[c*4+3]=f.w;
      }
#pragma unroll
      for (int j = 0; j < 16; j++) { s += xv[j]; sq += xv[j]*xv[j]; }
    } else {
#pragma unroll
      for (int j = 0; j < 16; j++) xv[j] = 0.f;
    }
    s += __shfl_xor(s, 1); s += __shfl_xor(s, 2); s += __shfl_xor(s, 4);
    sq += __shfl_xor(sq, 1); sq += __shfl_xor(sq, 2); sq += __shfl_xor(sq, 4);
    float m = s * (1.f / HDIM);
    float rv = rsqrtf(sq * (1.f / HDIM) - m * m + 1e-5f);
#pragma unroll
    for (int cb = 0; cb < 2; cb++) {
      ushort8 u;
#pragma unroll
      for (int j = 0; j < 8; j++) {
        int col = oct * 16 + cb * 8 + j;
        u[j] = f2bf((xv[cb*8+j] - m) * rv * g[col] + be[col]);
      }
      *(ushort8*)&xn[row][oct * 16 + cb * 8] = u;
    }
  }
  __syncthreads();
  int w = t >> 6, lane = t & 63;
  int rt = w & 1, r0 = rt * 16;
  int cthalf = w >> 1;
  short8 a[4];
#pragma unroll
  for (int kc = 0; kc < 4; kc++)
    a[kc] = *(const short8*)&xn[r0 + (lane & 15)][kc * 32 + (lane >> 4) * 8];
  // GEMM1: hidden = relu(xn @ W1 + b1), bf16 into LDS
  for (int ci = 0; ci < 16; ci++) {
    int ct = cthalf * 16 + ci;
    floatx4 acc = {0.f, 0.f, 0.f, 0.f};
#pragma unroll
    for (int kc = 0; kc < 4; kc++) {
      short8 b = *(const short8*)(W1f + ((size_t)(ct * 4 + kc) * 64 + lane) * 8);
      acc = __builtin_amdgcn_mfma_f32_16x16x32_bf16(a[kc], b, acc, 0, 0, 0);
    }
    int col = ct * 16 + (lane & 15);
    float bb = b1[col];
#pragma unroll
    for (int r = 0; r < 4; r++) {
      int rr = r0 + (lane >> 4) * 4 + r;
      hs[rr][col] = f2bf(fmaxf(acc[r] + bb, 0.f));
    }
  }
  __syncthreads();
  // GEMM2: out = hidden @ W2 + b2 + xin
  short8 ah[16];
#pragma unroll
  for (int kc = 0; kc < 16; kc++)
    ah[kc] = *(const short8*)&hs[r0 + (lane & 15)][kc * 32 + (lane >> 4) * 8];
  for (int ci = 0; ci < 4; ci++) {
    int ct = cthalf * 4 + ci;
    floatx4 acc = {0.f, 0.f, 0.f, 0.f};
#pragma unroll
    for (int kc = 0; kc < 16; kc++) {
      short8 b = *(const short8*)(W2f + ((size_t)(ct * 16 + kc) * 64 + lane) * 8);
      acc = __builtin_amdgcn_mfma_f32_16x16x32_bf16(ah[kc], b, acc, 0, 0, 0);
    }
    int col = ct * 16 + (lane & 15);
    float bb = b2[col];
#pragma unroll
    for (int r = 0; r < 4; r++) {
      int rr = r0 + (lane >> 4) * 4 + r;
      int nd = n0 + rr;
      if (nd < NN) {
        size_t idx = (size_t)nd * HDIM + col;
        x[idx] = xin[idx] + acc[r] + bb;
      }
    }
  }
}

// ---------------- final LN -> d_out ----------------
__global__ void k_final(const float* __restrict__ x, const float* __restrict__ g,
                        const float* __restrict__ be, float* __restrict__ outx) {
  __shared__ float xs[16][HDIM + 1];
  __shared__ float mv[16][2];
  int t = threadIdx.x;  // 128
  int n0 = blockIdx.x * 16;
  for (int nb = 0; nb < 16; nb++) {
    int node = n0 + nb;
    xs[nb][t] = (node < NN) ? x[node * HDIM + t] : 0.f;
  }
  __syncthreads();
  if (t < 16) {
    float m = 0.f;
    for (int i = 0; i < HDIM; i++) m += xs[t][i];
    m *= (1.f / HDIM);
    float var = 0.f;
    for (int i = 0; i < HDIM; i++) { float d = xs[t][i] - m; var += d * d; }
    var *= (1.f / HDIM);
    mv[t][0] = m;
    mv[t][1] = rsqrtf(var + 1e-5f);
  }
  __syncthreads();
  float gg = g[t], bb = be[t];
  for (int nb = 0; nb < 16; nb++) {
    int node = n0 + nb;
    if (node < NN) outx[node * HDIM + t] = (xs[nb][t] - mv[nb][0]) * mv[nb][1] * gg + bb;
  }
}

// ---------------- graph mean pooling (batch is sorted) ----------------
__global__ void k_pool(const float* __restrict__ outx, const int* __restrict__ gstart,
                       const int* __restrict__ gcnt, float* __restrict__ outg) {
  __shared__ float part[4][HDIM];
  int g = blockIdx.x;
  int t = threadIdx.x;  // 512
  int hd = t & 127, p = t >> 7;
  int s0 = gstart[g];
  int c = gcnt[g];
  float s = 0.f;
  for (int i = p; i < c; i += 4) s += outx[(size_t)(s0 + i) * HDIM + hd];
  part[p][hd] = s;
  __syncthreads();
  if (p == 0) {
    float tot = part[0][hd] + part[1][hd] + part[2][hd] + part[3][hd];
    outg[g * HDIM + hd] = tot / fmaxf((float)c, 1.f);
  }
}

extern "C" void kernel_launch(void* const* d_in, const int* in_sizes, int n_in,
                              void* d_out, int out_size, void* d_ws, size_t ws_size,
                              hipStream_t stream) {
  const float* h      = (const float*)d_in[0];
  const float* e      = (const float*)d_in[1];
  const int*   eidx   = (const int*)d_in[2];
  const int*   batch  = (const int*)d_in[3];
  const float* node_W = (const float*)d_in[4];
  const float* node_b = (const float*)d_in[5];
  const float* edge_W = (const float*)d_in[6];
  const float* edge_b = (const float*)d_in[7];
  const float* Wq  = (const float*)d_in[8];
  const float* bq  = (const float*)d_in[9];
  const float* Wk  = (const float*)d_in[10];
  const float* bk  = (const float*)d_in[11];
  const float* Wv  = (const float*)d_in[12];
  const float* bv  = (const float*)d_in[13];
  const float* Wo  = (const float*)d_in[14];
  const float* bo  = (const float*)d_in[15];
  const float* Web = (const float*)d_in[16];
  const float* beb = (const float*)d_in[17];
  const float* W1  = (const float*)d_in[18];
  const float* b1  = (const float*)d_in[19];
  const float* W2  = (const float*)d_in[20];
  const float* b2  = (const float*)d_in[21];
  const float* g1  = (const float*)d_in[22];
  const float* be1 = (const float*)d_in[23];
  const float* g2  = (const float*)d_in[24];
  const float* be2 = (const float*)d_in[25];
  const float* gF  = (const float*)d_in[26];
  const float* bF  = (const float*)d_in[27];

  const int* rowArr = eidx;
  const int* colArr = eidx + EE;

  char* ws = (char*)d_ws;
  size_t off = 0;
  auto alloc = [&](size_t bytes) -> void* {
    void* p = ws + off;
    off = (off + bytes + 255) & ~(size_t)255;
    return p;
  };
  float* x    = (float*)alloc((size_t)NN * HDIM * 4);
  unsigned short* qb = (unsigned short*)alloc((size_t)NN * HDIM * 2);
  unsigned short* kb = (unsigned short*)alloc((size_t)NN * HDIM * 2);
  unsigned short* vb = (unsigned short*)alloc((size_t)NN * HDIM * 2);
  unsigned short* ao = (unsigned short*)alloc((size_t)NN * HDIM * 2);
  int* deg    = (int*)alloc((size_t)NN * 4);
  int* starts = (int*)alloc((size_t)(NN + 1) * 4);
  int* cursor = (int*)alloc((size_t)NN * 4);
  int* eids   = (int*)alloc((size_t)EE * 4);
  float* Wcomb = (float*)alloc((size_t)LL * EDI * HH * 4);
  float* bcomb = (float*)alloc((size_t)LL * HH * 4);
  int* gcnt   = (int*)alloc((size_t)GG * 4);
  int* gstart = (int*)alloc((size_t)(GG + 1) * 4);
  // fragment-packed bf16 weights
  const int QKV_FRAG = 8 * 4 * 512;    // 16384 elems per matrix per layer
  const int FFN_FRAG1 = 32 * 4 * 512;  // 65536
  const int FFN_FRAG2 = 8 * 16 * 512;  // 65536
  unsigned short* Wqf = (unsigned short*)alloc((size_t)LL * QKV_FRAG * 2);
  unsigned short* Wkf = (unsigned short*)alloc((size_t)LL * QKV_FRAG * 2);
  unsigned short* Wvf = (unsigned short*)alloc((size_t)LL * QKV_FRAG * 2);
  unsigned short* Wof = (unsigned short*)alloc((size_t)LL * QKV_FRAG * 2);
  unsigned short* W1f = (unsigned short*)alloc((size_t)LL * FFN_FRAG1 * 2);
  unsigned short* W2f = (unsigned short*)alloc((size_t)LL * FFN_FRAG2 * 2);

  hipMemsetAsync(deg, 0, (size_t)NN * 4, stream);
  hipMemsetAsync(gcnt, 0, (size_t)GG * 4, stream);

  k_node_proj<<<(NN + 31) / 32, 128, 0, stream>>>(h, node_W, node_b, x);
  k_wcomb<<<1, 256, 0, stream>>>(edge_W, edge_b, Web, beb, Wcomb, bcomb);
  k_pack<<<(LL * QKV_FRAG + 255) / 256, 256, 0, stream>>>(Wq, Wqf, HDIM, HDIM, LL);
  k_pack<<<(LL * QKV_FRAG + 255) / 256, 256, 0, stream>>>(Wk, Wkf, HDIM, HDIM, LL);
  k_pack<<<(LL * QKV_FRAG + 255) / 256, 256, 0, stream>>>(Wv, Wvf, HDIM, HDIM, LL);
  k_pack<<<(LL * QKV_FRAG + 255) / 256, 256, 0, stream>>>(Wo, Wof, HDIM, HDIM, LL);
  k_pack<<<(LL * FFN_FRAG1 + 255) / 256, 256, 0, stream>>>(W1, W1f, HDIM, FFD, LL);
  k_pack<<<(LL * FFN_FRAG2 + 255) / 256, 256, 0, stream>>>(W2, W2f, FFD, HDIM, LL);
  k_deg<<<(EE + 255) / 256, 256, 0, stream>>>(rowArr, deg);
  k_scan<<<1, 1024, 0, stream>>>(deg, starts, cursor, NN);
  k_scatter<<<(EE + 255) / 256, 256, 0, stream>>>(rowArr, cursor, eids);
  k_gcnt<<<(NN + 255) / 256, 256, 0, stream>>>(batch, gcnt);
  k_bscan<<<1, 64, 0, stream>>>(gcnt, gstart);

  int nb64 = (NN + 63) / 64;
  int nb32 = (NN + 31) / 32;
  for (int l = 0; l < LL; l++) {
    k_ln_qkv_mfma<<<nb64, 256, 0, stream>>>(x,
        Wqf + (size_t)l * QKV_FRAG, bq + (size_t)l * HDIM,
        Wkf + (size_t)l * QKV_FRAG, bk + (size_t)l * HDIM,
        Wvf + (size_t)l * QKV_FRAG, bv + (size_t)l * HDIM,
        g1 + (size_t)l * HDIM, be1 + (size_t)l * HDIM, qb, kb, vb);
    k_attn<<<NN, 128, 0, stream>>>(qb, kb, vb, e, colArr, eids, starts,
        Wcomb + (size_t)l * EDI * HH, bcomb + (size_t)l * HH, ao);
    k_oproj_mfma<<<nb64, 256, 0, stream>>>(ao, Wof + (size_t)l * QKV_FRAG,
        bo + (size_t)l * HDIM, x);
    k_ffn_mfma<<<nb32, 256, 0, stream>>>(x,
        W1f + (size_t)l * FFN_FRAG1, b1 + (size_t)l * FFD,
        W2f + (size_t)l * FFN_FRAG2, b2 + (size_t)l * HDIM,
        g2 + (size_t)l * HDIM, be2 + (size_t)l * HDIM, x);
  }

  float* outx = (float*)d_out;
  float* outg = outx + (size_t)NN * HDIM;
  int nblk16 = (NN + 15) / 16;
  k_final<<<nblk16, 128, 0, stream>>>(x, gF, bF, outx);
  k_pool<<<GG, 512, 0, stream>>>(outx, gstart, gcnt, outg);
}

// Round 3
// 1685.607 us; speedup vs baseline: 2.9414x; 1.5453x over previous
//
#include <hip/hip_runtime.h>
#include <hip/hip_bf16.h>
#include <math.h>

#define NN 50000
#define EE 800000
#define HH 8
#define DD 16
#define HDIM 128
#define LL 6
#define GG 64
#define NDI 48
#define EDI 4
#define FFD 512

typedef __attribute__((ext_vector_type(8))) short short8;
typedef __attribute__((ext_vector_type(8))) unsigned short ushort8;
typedef __attribute__((ext_vector_type(4))) float floatx4;

__device__ __forceinline__ unsigned short f2bf(float f) {
  unsigned u = __builtin_bit_cast(unsigned, f);
  unsigned rnd = 0x7FFFu + ((u >> 16) & 1u);
  return (unsigned short)((u + rnd) >> 16);
}
__device__ __forceinline__ float bf2f(unsigned short u) {
  unsigned v = ((unsigned)u) << 16;
  return __builtin_bit_cast(float, v);
}

// ---------------- node input projection: x = h @ node_W + node_b (fp32) ----------------
__global__ void k_node_proj(const float* __restrict__ h, const float* __restrict__ W,
                            const float* __restrict__ b, float* __restrict__ x) {
  __shared__ float hs[32][NDI];
  int t = threadIdx.x;                 // 128
  int n0 = blockIdx.x * 32;
  for (int idx = t; idx < 32 * NDI; idx += 128) {
    int nb = idx / NDI, i = idx - nb * NDI;
    int node = n0 + nb;
    hs[nb][i] = (node < NN) ? h[node * NDI + i] : 0.f;
  }
  __syncthreads();
  float acc[32];
#pragma unroll
  for (int nb = 0; nb < 32; nb++) acc[nb] = 0.f;
  for (int i = 0; i < NDI; i++) {
    float w = W[i * HDIM + t];
#pragma unroll
    for (int nb = 0; nb < 32; nb++) acc[nb] += hs[nb][i] * w;
  }
  float bb = b[t];
  for (int nb = 0; nb < 32; nb++) {
    int node = n0 + nb;
    if (node < NN) x[node * HDIM + t] = acc[nb] + bb;
  }
}

// ------- weight fragment pre-pack: W[m][K][OC] fp32 -> [m][OC/16][K/32][64][8] bf16 -------
__global__ void k_pack(const float* __restrict__ W, unsigned short* __restrict__ dst,
                       int K, int OC, int nmat) {
  int KC = K >> 5, CT = OC >> 4;
  int total = nmat * CT * KC * 512;
  for (int i = blockIdx.x * 256 + threadIdx.x; i < total; i += gridDim.x * 256) {
    int j = i & 7;
    int lane = (i >> 3) & 63;
    int rest = i >> 9;
    int kc = rest % KC; rest /= KC;
    int ct = rest % CT; int m = rest / CT;
    int col = ct * 16 + (lane & 15);
    int k = kc * 32 + (lane >> 4) * 8 + j;
    dst[i] = f2bf(W[(size_t)m * K * OC + (size_t)k * OC + col]);
  }
}

// ------- combined edge-bias matrices: Wcomb[l] = edge_W @ Web[l]  [4x8], bcomb -------
__global__ void k_wcomb(const float* __restrict__ edge_W, const float* __restrict__ edge_b,
                        const float* __restrict__ Web, const float* __restrict__ beb,
                        float* __restrict__ Wcomb, float* __restrict__ bcomb) {
  int t = threadIdx.x;  // 256
  if (t < LL * EDI * HH) {  // 192
    int l = t / (EDI * HH);
    int i = (t / HH) % EDI;
    int hh = t % HH;
    float s = 0.f;
    for (int j = 0; j < HDIM; j++) s += edge_W[i * HDIM + j] * Web[(l * HDIM + j) * HH + hh];
    Wcomb[t] = s;
  } else if (t < LL * EDI * HH + LL * HH) {  // next 48
    int u = t - LL * EDI * HH;
    int l = u / HH, hh = u % HH;
    float s = beb[l * HH + hh];
    for (int j = 0; j < HDIM; j++) s += edge_b[j] * Web[(l * HDIM + j) * HH + hh];
    bcomb[u] = s;
  }
}

// ---------------- CSR build ----------------
__global__ void k_deg(const int* __restrict__ row, int* __restrict__ deg) {
  int e = blockIdx.x * 256 + threadIdx.x;
  if (e < EE) atomicAdd(&deg[row[e]], 1);
}

__global__ void k_scan(const int* __restrict__ deg, int* __restrict__ starts,
                       int* __restrict__ cursor, int n) {
  __shared__ int sdata[1024];
  __shared__ int s_running;
  int tid = threadIdx.x;
  if (tid == 0) s_running = 0;
  __syncthreads();
  for (int base = 0; base < n; base += 1024) {
    int i = base + tid;
    int v = (i < n) ? deg[i] : 0;
    sdata[tid] = v;
    __syncthreads();
    for (int off = 1; off < 1024; off <<= 1) {
      int tv = (tid >= off) ? sdata[tid - off] : 0;
      __syncthreads();
      sdata[tid] += tv;
      __syncthreads();
    }
    int excl = sdata[tid] - v;
    int total = sdata[1023];
    int sval = s_running + excl;
    if (i < n) { starts[i] = sval; cursor[i] = sval; }
    __syncthreads();
    if (tid == 0) s_running += total;
    __syncthreads();
  }
  if (tid == 0) starts[n] = s_running;
}

__global__ void k_scatter(const int* __restrict__ row, int* __restrict__ cursor,
                          int* __restrict__ eids) {
  int e = blockIdx.x * 256 + threadIdx.x;
  if (e < EE) {
    int r = row[e];
    int pos = atomicAdd(&cursor[r], 1);
    eids[pos] = e;
  }
}

__global__ void k_gcnt(const int* __restrict__ batch, int* __restrict__ gcnt) {
  int i = blockIdx.x * 256 + threadIdx.x;
  if (i < NN) atomicAdd(&gcnt[batch[i]], 1);
}

__global__ void k_bscan(const int* __restrict__ gcnt, int* __restrict__ gstart) {
  if (threadIdx.x == 0) {
    int s = 0;
    for (int g = 0; g < GG; g++) { gstart[g] = s; s += gcnt[g]; }
    gstart[GG] = s;
  }
}

// ---------------- LN1 + QKV projection via MFMA: 64 nodes/block, 4 waves ----------------
__global__ __launch_bounds__(256) void k_ln_qkv_mfma(
    const float* __restrict__ x,
    const unsigned short* __restrict__ Wqf, const float* __restrict__ bq,
    const unsigned short* __restrict__ Wkf, const float* __restrict__ bk,
    const unsigned short* __restrict__ Wvf, const float* __restrict__ bv,
    const float* __restrict__ g, const float* __restrict__ be,
    unsigned short* __restrict__ q, unsigned short* __restrict__ k,
    unsigned short* __restrict__ v) {
  __shared__ unsigned short xn[64][136];
  int t = threadIdx.x;
  int n0 = blockIdx.x * 64;
  {
    int row = t >> 2, quad = t & 3;   // 4 lanes/row, 32 elems each
    int node = n0 + row;
    float xv[32];
    float s = 0.f, sq = 0.f;
    if (node < NN) {
      const float* xr = x + (size_t)node * HDIM + quad * 32;
#pragma unroll
      for (int c = 0; c < 8; c++) {
        float4 f = *(const float4*)(xr + c * 4);
        xv[c*4+0]=f.x; xv[c*4+1]=f.y; xv[c*4+2]=f.z; xv[c*4+3]=f.w;
      }
#pragma unroll
      for (int j = 0; j < 32; j++) { s += xv[j]; sq += xv[j]*xv[j]; }
    } else {
#pragma unroll
      for (int j = 0; j < 32; j++) xv[j] = 0.f;
    }
    s += __shfl_xor(s, 1); s += __shfl_xor(s, 2);
    sq += __shfl_xor(sq, 1); sq += __shfl_xor(sq, 2);
    float m = s * (1.f / HDIM);
    float rv = rsqrtf(sq * (1.f / HDIM) - m * m + 1e-5f);
#pragma unroll
    for (int cb = 0; cb < 4; cb++) {
      ushort8 u;
#pragma unroll
      for (int j = 0; j < 8; j++) {
        int col = quad * 32 + cb * 8 + j;
        u[j] = f2bf((xv[cb*8+j] - m) * rv * g[col] + be[col]);
      }
      *(ushort8*)&xn[row][quad * 32 + cb * 8] = u;
    }
  }
  __syncthreads();
  int w = t >> 6, lane = t & 63;
  int r0 = w * 16;
  short8 a[4];
#pragma unroll
  for (int kc = 0; kc < 4; kc++)
    a[kc] = *(const short8*)&xn[r0 + (lane & 15)][kc * 32 + (lane >> 4) * 8];
  const unsigned short* Wf[3] = {Wqf, Wkf, Wvf};
  const float* bias[3] = {bq, bk, bv};
  unsigned short* outp[3] = {q, k, v};
#pragma unroll
  for (int mm = 0; mm < 3; mm++) {
    const unsigned short* wf = Wf[mm];
    for (int ct = 0; ct < 8; ct++) {
      floatx4 acc = {0.f, 0.f, 0.f, 0.f};
#pragma unroll
      for (int kc = 0; kc < 4; kc++) {
        short8 b = *(const short8*)(wf + ((size_t)(ct * 4 + kc) * 64 + lane) * 8);
        acc = __builtin_amdgcn_mfma_f32_16x16x32_bf16(a[kc], b, acc, 0, 0, 0);
      }
      int col = ct * 16 + (lane & 15);
      float bb = bias[mm][col];
#pragma unroll
      for (int r = 0; r < 4; r++) {
        int rr = r0 + (lane >> 4) * 4 + r;
        int nd = n0 + rr;
        if (nd < NN) outp[mm][(size_t)nd * HDIM + col] = f2bf(acc[r] + bb);
      }
    }
  }
}

// ---------------- attention: one wave per node, vectorized gathers, 2-deep pipeline ----
__global__ __launch_bounds__(256) void k_attn(
    const unsigned short* __restrict__ q, const unsigned short* __restrict__ k,
    const unsigned short* __restrict__ v, const float* __restrict__ efeat,
    const int* __restrict__ colArr, const int* __restrict__ eids,
    const int* __restrict__ starts,
    const float* __restrict__ Wcomb, const float* __restrict__ bcomb,
    unsigned short* __restrict__ out) {
  int t = threadIdx.x;
  int wave = t >> 6, lane = t & 63;
  int node = blockIdx.x * 4 + wave;
  if (node >= NN) return;
  int g = lane >> 4, d = lane & 15;
  int hh = d >> 1;                      // head owned by this lane

  // per-lane q slice (scale folded in)
  float qf[8];
  {
    ushort8 q8 = *(const ushort8*)(q + (size_t)node * HDIM + d * 8);
#pragma unroll
    for (int j = 0; j < 8; j++) qf[j] = bf2f(q8[j]) * 0.25f;
  }
  float wc0 = Wcomb[0 * HH + hh], wc1 = Wcomb[1 * HH + hh];
  float wc2 = Wcomb[2 * HH + hh], wc3 = Wcomb[3 * HH + hh];
  float bc = bcomb[hh];

  int s0 = starts[node], s1 = starts[node + 1];
  float acc[8];
#pragma unroll
  for (int j = 0; j < 8; j++) acc[j] = 0.f;
  float lsum = 0.f;

  // pipeline prologue: ids for chunk0 and chunk1, data for chunk0
  int i0 = s0 + g;
  int e0 = (i0 < s1) ? eids[i0] : -1;
  int c0 = (e0 >= 0) ? colArr[e0] : 0;
  int i1 = s0 + 4 + g;
  int e1 = (i1 < s1) ? eids[i1] : -1;
  int c1 = (e1 >= 0) ? colArr[e1] : 0;
  ushort8 k8 = *(const ushort8*)(k + (size_t)c0 * HDIM + d * 8);
  ushort8 v8 = *(const ushort8*)(v + (size_t)c0 * HDIM + d * 8);
  float4 ef = (e0 >= 0) ? *(const float4*)(efeat + (size_t)e0 * EDI)
                        : float4{0.f, 0.f, 0.f, 0.f};

  for (int base = s0; base < s1; base += 4) {
    // issue next chunk's heavy gathers (addresses already known)
    int cn = c1;
    ushort8 k8n = *(const ushort8*)(k + (size_t)cn * HDIM + d * 8);
    ushort8 v8n = *(const ushort8*)(v + (size_t)cn * HDIM + d * 8);
    float4 efn = (e1 >= 0) ? *(const float4*)(efeat + (size_t)e1 * EDI)
                           : float4{0.f, 0.f, 0.f, 0.f};
    // issue ids for chunk i+2
    int i2 = base + 8 + g;
    int e2 = (i2 < s1) ? eids[i2] : -1;
    int c2 = (e2 >= 0) ? colArr[e2] : 0;

    // compute with current chunk
    bool valid = (e0 >= 0);
    float part = 0.f;
#pragma unroll
    for (int j = 0; j < 8; j++) part += qf[j] * bf2f(k8[j]);
    part += __shfl_xor(part, 1);        // head sum (lanes 2h,2h+1)
    float eb = bc + ef.x * wc0 + ef.y * wc1 + ef.z * wc2 + ef.w * wc3;
    float ex = valid ? __expf(part + eb) : 0.f;
    lsum += ex;
#pragma unroll
    for (int j = 0; j < 8; j++) acc[j] += ex * bf2f(v8[j]);

    // rotate pipeline
    e0 = e1; c0 = c1; k8 = k8n; v8 = v8n; ef = efn;
    e1 = e2; c1 = c2;
  }

  // cross-group reduction (4 groups at lane stride 16)
#pragma unroll
  for (int j = 0; j < 8; j++) {
    acc[j] += __shfl_xor(acc[j], 16);
    acc[j] += __shfl_xor(acc[j], 32);
  }
  lsum += __shfl_xor(lsum, 16);
  lsum += __shfl_xor(lsum, 32);

  if (g == 0) {
    float inv = 1.f / (lsum + 1e-10f);
    ushort8 o;
#pragma unroll
    for (int j = 0; j < 8; j++) o[j] = f2bf(acc[j] * inv);
    *(ushort8*)(out + (size_t)node * HDIM + d * 8) = o;
  }
}

// ---------------- out-projection + residual via MFMA ----------------
__global__ __launch_bounds__(256) void k_oproj_mfma(
    const unsigned short* __restrict__ ao, const unsigned short* __restrict__ Wof,
    const float* __restrict__ bo, float* __restrict__ x) {
  __shared__ unsigned short aos[64][136];
  int t = threadIdx.x;
  int n0 = blockIdx.x * 64;
#pragma unroll
  for (int c = 0; c < 4; c++) {
    int elem = c * 2048 + t * 8;
    int row = elem >> 7, col = elem & 127;
    int nd = n0 + row;
    ushort8 u = {0, 0, 0, 0, 0, 0, 0, 0};
    if (nd < NN) u = *(const ushort8*)(ao + (size_t)nd * HDIM + col);
    *(ushort8*)&aos[row][col] = u;
  }
  __syncthreads();
  int w = t >> 6, lane = t & 63;
  int r0 = w * 16;
  short8 a[4];
#pragma unroll
  for (int kc = 0; kc < 4; kc++)
    a[kc] = *(const short8*)&aos[r0 + (lane & 15)][kc * 32 + (lane >> 4) * 8];
  for (int ct = 0; ct < 8; ct++) {
    floatx4 acc = {0.f, 0.f, 0.f, 0.f};
#pragma unroll
    for (int kc = 0; kc < 4; kc++) {
      short8 b = *(const short8*)(Wof + ((size_t)(ct * 4 + kc) * 64 + lane) * 8);
      acc = __builtin_amdgcn_mfma_f32_16x16x32_bf16(a[kc], b, acc, 0, 0, 0);
    }
    int col = ct * 16 + (lane & 15);
    float bb = bo[col];
#pragma unroll
    for (int r = 0; r < 4; r++) {
      int rr = r0 + (lane >> 4) * 4 + r;
      int nd = n0 + rr;
      if (nd < NN) {
        size_t idx = (size_t)nd * HDIM + col;
        x[idx] = x[idx] + acc[r] + bb;
      }
    }
  }
}

// ---------------- LN2 + FFN + residual via MFMA: 32 nodes/block ----------------
__global__ __launch_bounds__(256) void k_ffn_mfma(
    const float* __restrict__ xin,
    const unsigned short* __restrict__ W1f, const float* __restrict__ b1,
    const unsigned short* __restrict__ W2f, const float* __restrict__ b2,
    const float* __restrict__ g, const float* __restrict__ be,
    float* __restrict__ x) {
  __shared__ unsigned short xn[32][136];
  __shared__ unsigned short hs[32][520];
  int t = threadIdx.x;
  int n0 = blockIdx.x * 32;
  {
    int row = t >> 3, oct = t & 7;   // 8 lanes/row, 16 elems each
    int node = n0 + row;
    float xv[16];
    float s = 0.f, sq = 0.f;
    if (node < NN) {
      const float* xr = xin + (size_t)node * HDIM + oct * 16;
#pragma unroll
      for (int c = 0; c < 4; c++) {
        float4 f = *(const float4*)(xr + c * 4);
        xv[c*4+0]=f.x; xv[c*4+1]=f.y; xv[c*4+2]=f.z; xv[c*4+3]=f.w;
      }
#pragma unroll
      for (int j = 0; j < 16; j++) { s += xv[j]; sq += xv[j]*xv[j]; }
    } else {
#pragma unroll
      for (int j = 0; j < 16; j++) xv[j] = 0.f;
    }
    s += __shfl_xor(s, 1); s += __shfl_xor(s, 2); s += __shfl_xor(s, 4);
    sq += __shfl_xor(sq, 1); sq += __shfl_xor(sq, 2); sq += __shfl_xor(sq, 4);
    float m = s * (1.f / HDIM);
    float rv = rsqrtf(sq * (1.f / HDIM) - m * m + 1e-5f);
#pragma unroll
    for (int cb = 0; cb < 2; cb++) {
      ushort8 u;
#pragma unroll
      for (int j = 0; j < 8; j++) {
        int col = oct * 16 + cb * 8 + j;
        u[j] = f2bf((xv[cb*8+j] - m) * rv * g[col] + be[col]);
      }
      *(ushort8*)&xn[row][oct * 16 + cb * 8] = u;
    }
  }
  __syncthreads();
  int w = t >> 6, lane = t & 63;
  int rt = w & 1, r0 = rt * 16;
  int cthalf = w >> 1;
  short8 a[4];
#pragma unroll
  for (int kc = 0; kc < 4; kc++)
    a[kc] = *(const short8*)&xn[r0 + (lane & 15)][kc * 32 + (lane >> 4) * 8];
  // GEMM1: hidden = relu(xn @ W1 + b1), bf16 into LDS
  for (int ci = 0; ci < 16; ci++) {
    int ct = cthalf * 16 + ci;
    floatx4 acc = {0.f, 0.f, 0.f, 0.f};
#pragma unroll
    for (int kc = 0; kc < 4; kc++) {
      short8 b = *(const short8*)(W1f + ((size_t)(ct * 4 + kc) * 64 + lane) * 8);
      acc = __builtin_amdgcn_mfma_f32_16x16x32_bf16(a[kc], b, acc, 0, 0, 0);
    }
    int col = ct * 16 + (lane & 15);
    float bb = b1[col];
#pragma unroll
    for (int r = 0; r < 4; r++) {
      int rr = r0 + (lane >> 4) * 4 + r;
      hs[rr][col] = f2bf(fmaxf(acc[r] + bb, 0.f));
    }
  }
  __syncthreads();
  // GEMM2: out = hidden @ W2 + b2 + xin
  short8 ah[16];
#pragma unroll
  for (int kc = 0; kc < 16; kc++)
    ah[kc] = *(const short8*)&hs[r0 + (lane & 15)][kc * 32 + (lane >> 4) * 8];
  for (int ci = 0; ci < 4; ci++) {
    int ct = cthalf * 4 + ci;
    floatx4 acc = {0.f, 0.f, 0.f, 0.f};
#pragma unroll
    for (int kc = 0; kc < 16; kc++) {
      short8 b = *(const short8*)(W2f + ((size_t)(ct * 16 + kc) * 64 + lane) * 8);
      acc = __builtin_amdgcn_mfma_f32_16x16x32_bf16(ah[kc], b, acc, 0, 0, 0);
    }
    int col = ct * 16 + (lane & 15);
    float bb = b2[col];
#pragma unroll
    for (int r = 0; r < 4; r++) {
      int rr = r0 + (lane >> 4) * 4 + r;
      int nd = n0 + rr;
      if (nd < NN) {
        size_t idx = (size_t)nd * HDIM + col;
        x[idx] = xin[idx] + acc[r] + bb;
      }
    }
  }
}

// ---------------- final LN -> d_out ----------------
__global__ void k_final(const float* __restrict__ x, const float* __restrict__ g,
                        const float* __restrict__ be, float* __restrict__ outx) {
  __shared__ float xs[16][HDIM + 1];
  __shared__ float mv[16][2];
  int t = threadIdx.x;  // 128
  int n0 = blockIdx.x * 16;
  for (int nb = 0; nb < 16; nb++) {
    int node = n0 + nb;
    xs[nb][t] = (node < NN) ? x[node * HDIM + t] : 0.f;
  }
  __syncthreads();
  if (t < 16) {
    float m = 0.f;
    for (int i = 0; i < HDIM; i++) m += xs[t][i];
    m *= (1.f / HDIM);
    float var = 0.f;
    for (int i = 0; i < HDIM; i++) { float d = xs[t][i] - m; var += d * d; }
    var *= (1.f / HDIM);
    mv[t][0] = m;
    mv[t][1] = rsqrtf(var + 1e-5f);
  }
  __syncthreads();
  float gg = g[t], bb = be[t];
  for (int nb = 0; nb < 16; nb++) {
    int node = n0 + nb;
    if (node < NN) outx[node * HDIM + t] = (xs[nb][t] - mv[nb][0]) * mv[nb][1] * gg + bb;
  }
}

// ---------------- graph mean pooling (batch is sorted) ----------------
__global__ void k_pool(const float* __restrict__ outx, const int* __restrict__ gstart,
                       const int* __restrict__ gcnt, float* __restrict__ outg) {
  __shared__ float part[4][HDIM];
  int g = blockIdx.x;
  int t = threadIdx.x;  // 512
  int hd = t & 127, p = t >> 7;
  int s0 = gstart[g];
  int c = gcnt[g];
  float s = 0.f;
  for (int i = p; i < c; i += 4) s += outx[(size_t)(s0 + i) * HDIM + hd];
  part[p][hd] = s;
  __syncthreads();
  if (p == 0) {
    float tot = part[0][hd] + part[1][hd] + part[2][hd] + part[3][hd];
    outg[g * HDIM + hd] = tot / fmaxf((float)c, 1.f);
  }
}

extern "C" void kernel_launch(void* const* d_in, const int* in_sizes, int n_in,
                              void* d_out, int out_size, void* d_ws, size_t ws_size,
                              hipStream_t stream) {
  const float* h      = (const float*)d_in[0];
  const float* e      = (const float*)d_in[1];
  const int*   eidx   = (const int*)d_in[2];
  const int*   batch  = (const int*)d_in[3];
  const float* node_W = (const float*)d_in[4];
  const float* node_b = (const float*)d_in[5];
  const float* edge_W = (const float*)d_in[6];
  const float* edge_b = (const float*)d_in[7];
  const float* Wq  = (const float*)d_in[8];
  const float* bq  = (const float*)d_in[9];
  const float* Wk  = (const float*)d_in[10];
  const float* bk  = (const float*)d_in[11];
  const float* Wv  = (const float*)d_in[12];
  const float* bv  = (const float*)d_in[13];
  const float* Wo  = (const float*)d_in[14];
  const float* bo  = (const float*)d_in[15];
  const float* Web = (const float*)d_in[16];
  const float* beb = (const float*)d_in[17];
  const float* W1  = (const float*)d_in[18];
  const float* b1  = (const float*)d_in[19];
  const float* W2  = (const float*)d_in[20];
  const float* b2  = (const float*)d_in[21];
  const float* g1  = (const float*)d_in[22];
  const float* be1 = (const float*)d_in[23];
  const float* g2  = (const float*)d_in[24];
  const float* be2 = (const float*)d_in[25];
  const float* gF  = (const float*)d_in[26];
  const float* bF  = (const float*)d_in[27];

  const int* rowArr = eidx;
  const int* colArr = eidx + EE;

  char* ws = (char*)d_ws;
  size_t off = 0;
  auto alloc = [&](size_t bytes) -> void* {
    void* p = ws + off;
    off = (off + bytes + 255) & ~(size_t)255;
    return p;
  };
  float* x    = (float*)alloc((size_t)NN * HDIM * 4);
  unsigned short* qb = (unsigned short*)alloc((size_t)NN * HDIM * 2);
  unsigned short* kb = (unsigned short*)alloc((size_t)NN * HDIM * 2);
  unsigned short* vb = (unsigned short*)alloc((size_t)NN * HDIM * 2);
  unsigned short* ao = (unsigned short*)alloc((size_t)NN * HDIM * 2);
  int* deg    = (int*)alloc((size_t)NN * 4);
  int* starts = (int*)alloc((size_t)(NN + 1) * 4);
  int* cursor = (int*)alloc((size_t)NN * 4);
  int* eids   = (int*)alloc((size_t)EE * 4);
  float* Wcomb = (float*)alloc((size_t)LL * EDI * HH * 4);
  float* bcomb = (float*)alloc((size_t)LL * HH * 4);
  int* gcnt   = (int*)alloc((size_t)GG * 4);
  int* gstart = (int*)alloc((size_t)(GG + 1) * 4);
  // fragment-packed bf16 weights
  const int QKV_FRAG = 8 * 4 * 512;    // 16384 elems per matrix per layer
  const int FFN_FRAG1 = 32 * 4 * 512;  // 65536
  const int FFN_FRAG2 = 8 * 16 * 512;  // 65536
  unsigned short* Wqf = (unsigned short*)alloc((size_t)LL * QKV_FRAG * 2);
  unsigned short* Wkf = (unsigned short*)alloc((size_t)LL * QKV_FRAG * 2);
  unsigned short* Wvf = (unsigned short*)alloc((size_t)LL * QKV_FRAG * 2);
  unsigned short* Wof = (unsigned short*)alloc((size_t)LL * QKV_FRAG * 2);
  unsigned short* W1f = (unsigned short*)alloc((size_t)LL * FFN_FRAG1 * 2);
  unsigned short* W2f = (unsigned short*)alloc((size_t)LL * FFN_FRAG2 * 2);

  hipMemsetAsync(deg, 0, (size_t)NN * 4, stream);
  hipMemsetAsync(gcnt, 0, (size_t)GG * 4, stream);

  k_node_proj<<<(NN + 31) / 32, 128, 0, stream>>>(h, node_W, node_b, x);
  k_wcomb<<<1, 256, 0, stream>>>(edge_W, edge_b, Web, beb, Wcomb, bcomb);
  k_pack<<<(LL * QKV_FRAG + 255) / 256, 256, 0, stream>>>(Wq, Wqf, HDIM, HDIM, LL);
  k_pack<<<(LL * QKV_FRAG + 255) / 256, 256, 0, stream>>>(Wk, Wkf, HDIM, HDIM, LL);
  k_pack<<<(LL * QKV_FRAG + 255) / 256, 256, 0, stream>>>(Wv, Wvf, HDIM, HDIM, LL);
  k_pack<<<(LL * QKV_FRAG + 255) / 256, 256, 0, stream>>>(Wo, Wof, HDIM, HDIM, LL);
  k_pack<<<(LL * FFN_FRAG1 + 255) / 256, 256, 0, stream>>>(W1, W1f, HDIM, FFD, LL);
  k_pack<<<(LL * FFN_FRAG2 + 255) / 256, 256, 0, stream>>>(W2, W2f, FFD, HDIM, LL);
  k_deg<<<(EE + 255) / 256, 256, 0, stream>>>(rowArr, deg);
  k_scan<<<1, 1024, 0, stream>>>(deg, starts, cursor, NN);
  k_scatter<<<(EE + 255) / 256, 256, 0, stream>>>(rowArr, cursor, eids);
  k_gcnt<<<(NN + 255) / 256, 256, 0, stream>>>(batch, gcnt);
  k_bscan<<<1, 64, 0, stream>>>(gcnt, gstart);

  int nb64 = (NN + 63) / 64;
  int nb32 = (NN + 31) / 32;
  for (int l = 0; l < LL; l++) {
    k_ln_qkv_mfma<<<nb64, 256, 0, stream>>>(x,
        Wqf + (size_t)l * QKV_FRAG, bq + (size_t)l * HDIM,
        Wkf + (size_t)l * QKV_FRAG, bk + (size_t)l * HDIM,
        Wvf + (size_t)l * QKV_FRAG, bv + (size_t)l * HDIM,
        g1 + (size_t)l * HDIM, be1 + (size_t)l * HDIM, qb, kb, vb);
    k_attn<<<(NN + 3) / 4, 256, 0, stream>>>(qb, kb, vb, e, colArr, eids, starts,
        Wcomb + (size_t)l * EDI * HH, bcomb + (size_t)l * HH, ao);
    k_oproj_mfma<<<nb64, 256, 0, stream>>>(ao, Wof + (size_t)l * QKV_FRAG,
        bo + (size_t)l * HDIM, x);
    k_ffn_mfma<<<nb32, 256, 0, stream>>>(x,
        W1f + (size_t)l * FFN_FRAG1, b1 + (size_t)l * FFD,
        W2f + (size_t)l * FFN_FRAG2, b2 + (size_t)l * HDIM,
        g2 + (size_t)l * HDIM, be2 + (size_t)l * HDIM, x);
  }

  float* outx = (float*)d_out;
  float* outg = outx + (size_t)NN * HDIM;
  int nblk16 = (NN + 15) / 16;
  k_final<<<nblk16, 128, 0, stream>>>(x, gF, bF, outx);
  k_pool<<<GG, 512, 0, stream>>>(outx, gstart, gcnt, outg);
}

// Round 4
// 1452.064 us; speedup vs baseline: 3.4144x; 1.1608x over previous
//
#include <hip/hip_runtime.h>
#include <hip/hip_bf16.h>
#include <math.h>

#define NN 50000
#define EE 800000
#define HH 8
#define DD 16
#define HDIM 128
#define LL 6
#define GG 64
#define NDI 48
#define EDI 4
#define FFD 512

typedef __attribute__((ext_vector_type(8))) short short8;
typedef __attribute__((ext_vector_type(8))) unsigned short ushort8;
typedef __attribute__((ext_vector_type(4))) float floatx4;

__device__ __forceinline__ unsigned short f2bf(float f) {
  unsigned u = __builtin_bit_cast(unsigned, f);
  unsigned rnd = 0x7FFFu + ((u >> 16) & 1u);
  return (unsigned short)((u + rnd) >> 16);
}
__device__ __forceinline__ float bf2f(unsigned short u) {
  unsigned v = ((unsigned)u) << 16;
  return __builtin_bit_cast(float, v);
}

// ---------------- node input projection: x = h @ node_W + node_b (fp32) ----------------
__global__ void k_node_proj(const float* __restrict__ h, const float* __restrict__ W,
                            const float* __restrict__ b, float* __restrict__ x) {
  __shared__ float hs[32][NDI];
  int t = threadIdx.x;                 // 128
  int n0 = blockIdx.x * 32;
  for (int idx = t; idx < 32 * NDI; idx += 128) {
    int nb = idx / NDI, i = idx - nb * NDI;
    int node = n0 + nb;
    hs[nb][i] = (node < NN) ? h[node * NDI + i] : 0.f;
  }
  __syncthreads();
  float acc[32];
#pragma unroll
  for (int nb = 0; nb < 32; nb++) acc[nb] = 0.f;
  for (int i = 0; i < NDI; i++) {
    float w = W[i * HDIM + t];
#pragma unroll
    for (int nb = 0; nb < 32; nb++) acc[nb] += hs[nb][i] * w;
  }
  float bb = b[t];
  for (int nb = 0; nb < 32; nb++) {
    int node = n0 + nb;
    if (node < NN) x[node * HDIM + t] = acc[nb] + bb;
  }
}

// ------- weight fragment pre-pack: W[m][K][OC] fp32 -> [m][OC/16][K/32][64][8] bf16 -------
__global__ void k_pack(const float* __restrict__ W, unsigned short* __restrict__ dst,
                       int K, int OC, int nmat) {
  int KC = K >> 5, CT = OC >> 4;
  int total = nmat * CT * KC * 512;
  for (int i = blockIdx.x * 256 + threadIdx.x; i < total; i += gridDim.x * 256) {
    int j = i & 7;
    int lane = (i >> 3) & 63;
    int rest = i >> 9;
    int kc = rest % KC; rest /= KC;
    int ct = rest % CT; int m = rest / CT;
    int col = ct * 16 + (lane & 15);
    int k = kc * 32 + (lane >> 4) * 8 + j;
    dst[i] = f2bf(W[(size_t)m * K * OC + (size_t)k * OC + col]);
  }
}

// ------- combined edge-bias matrices: Wcomb[l] = edge_W @ Web[l]  [4x8], bcomb -------
__global__ void k_wcomb(const float* __restrict__ edge_W, const float* __restrict__ edge_b,
                        const float* __restrict__ Web, const float* __restrict__ beb,
                        float* __restrict__ Wcomb, float* __restrict__ bcomb) {
  int t = threadIdx.x;  // 256
  if (t < LL * EDI * HH) {  // 192
    int l = t / (EDI * HH);
    int i = (t / HH) % EDI;
    int hh = t % HH;
    float s = 0.f;
    for (int j = 0; j < HDIM; j++) s += edge_W[i * HDIM + j] * Web[(l * HDIM + j) * HH + hh];
    Wcomb[t] = s;
  } else if (t < LL * EDI * HH + LL * HH) {  // next 48
    int u = t - LL * EDI * HH;
    int l = u / HH, hh = u % HH;
    float s = beb[l * HH + hh];
    for (int j = 0; j < HDIM; j++) s += edge_b[j] * Web[(l * HDIM + j) * HH + hh];
    bcomb[u] = s;
  }
}

// ---------------- CSR build ----------------
__global__ void k_deg(const int* __restrict__ row, int* __restrict__ deg) {
  int e = blockIdx.x * 256 + threadIdx.x;
  if (e < EE) atomicAdd(&deg[row[e]], 1);
}

__global__ void k_scan(const int* __restrict__ deg, int* __restrict__ starts,
                       int* __restrict__ cursor, int n) {
  __shared__ int sdata[1024];
  __shared__ int s_running;
  int tid = threadIdx.x;
  if (tid == 0) s_running = 0;
  __syncthreads();
  for (int base = 0; base < n; base += 1024) {
    int i = base + tid;
    int v = (i < n) ? deg[i] : 0;
    sdata[tid] = v;
    __syncthreads();
    for (int off = 1; off < 1024; off <<= 1) {
      int tv = (tid >= off) ? sdata[tid - off] : 0;
      __syncthreads();
      sdata[tid] += tv;
      __syncthreads();
    }
    int excl = sdata[tid] - v;
    int total = sdata[1023];
    int sval = s_running + excl;
    if (i < n) { starts[i] = sval; cursor[i] = sval; }
    __syncthreads();
    if (tid == 0) s_running += total;
    __syncthreads();
  }
  if (tid == 0) starts[n] = s_running;
}

__global__ void k_scatter(const int* __restrict__ row, int* __restrict__ cursor,
                          int* __restrict__ eids) {
  int e = blockIdx.x * 256 + threadIdx.x;
  if (e < EE) {
    int r = row[e];
    int pos = atomicAdd(&cursor[r], 1);
    eids[pos] = e;
  }
}

// ---------------- graph ranges from sorted batch: boundary detection ----------------
__global__ void k_gbounds(const int* __restrict__ batch, int* __restrict__ gstart) {
  int i = blockIdx.x * 256 + threadIdx.x;
  if (i >= NN) return;
  int b = batch[i];
  int prev = (i == 0) ? -1 : batch[i - 1];
  for (int g = prev + 1; g <= b; g++) gstart[g] = i;
  if (i == NN - 1) {
    for (int g = b + 1; g <= GG; g++) gstart[g] = NN;
  }
}

// ---------------- LN1 + QKV projection via MFMA: 64 nodes/block, 4 waves ----------------
__global__ __launch_bounds__(256) void k_ln_qkv_mfma(
    const float* __restrict__ x,
    const unsigned short* __restrict__ Wqf, const float* __restrict__ bq,
    const unsigned short* __restrict__ Wkf, const float* __restrict__ bk,
    const unsigned short* __restrict__ Wvf, const float* __restrict__ bv,
    const float* __restrict__ g, const float* __restrict__ be,
    unsigned short* __restrict__ q, unsigned short* __restrict__ k,
    unsigned short* __restrict__ v) {
  __shared__ unsigned short xn[64][136];
  int t = threadIdx.x;
  int n0 = blockIdx.x * 64;
  {
    int row = t >> 2, quad = t & 3;   // 4 lanes/row, 32 elems each
    int node = n0 + row;
    float xv[32];
    float s = 0.f, sq = 0.f;
    if (node < NN) {
      const float* xr = x + (size_t)node * HDIM + quad * 32;
#pragma unroll
      for (int c = 0; c < 8; c++) {
        float4 f = *(const float4*)(xr + c * 4);
        xv[c*4+0]=f.x; xv[c*4+1]=f.y; xv[c*4+2]=f.z; xv[c*4+3]=f.w;
      }
#pragma unroll
      for (int j = 0; j < 32; j++) { s += xv[j]; sq += xv[j]*xv[j]; }
    } else {
#pragma unroll
      for (int j = 0; j < 32; j++) xv[j] = 0.f;
    }
    s += __shfl_xor(s, 1); s += __shfl_xor(s, 2);
    sq += __shfl_xor(sq, 1); sq += __shfl_xor(sq, 2);
    float m = s * (1.f / HDIM);
    float rv = rsqrtf(sq * (1.f / HDIM) - m * m + 1e-5f);
#pragma unroll
    for (int cb = 0; cb < 4; cb++) {
      ushort8 u;
#pragma unroll
      for (int j = 0; j < 8; j++) {
        int col = quad * 32 + cb * 8 + j;
        u[j] = f2bf((xv[cb*8+j] - m) * rv * g[col] + be[col]);
      }
      *(ushort8*)&xn[row][quad * 32 + cb * 8] = u;
    }
  }
  __syncthreads();
  int w = t >> 6, lane = t & 63;
  int r0 = w * 16;
  short8 a[4];
#pragma unroll
  for (int kc = 0; kc < 4; kc++)
    a[kc] = *(const short8*)&xn[r0 + (lane & 15)][kc * 32 + (lane >> 4) * 8];
  const unsigned short* Wf[3] = {Wqf, Wkf, Wvf};
  const float* bias[3] = {bq, bk, bv};
  unsigned short* outp[3] = {q, k, v};
#pragma unroll
  for (int mm = 0; mm < 3; mm++) {
    const unsigned short* wf = Wf[mm];
    for (int ct = 0; ct < 8; ct++) {
      floatx4 acc = {0.f, 0.f, 0.f, 0.f};
#pragma unroll
      for (int kc = 0; kc < 4; kc++) {
        short8 b = *(const short8*)(wf + ((size_t)(ct * 4 + kc) * 64 + lane) * 8);
        acc = __builtin_amdgcn_mfma_f32_16x16x32_bf16(a[kc], b, acc, 0, 0, 0);
      }
      int col = ct * 16 + (lane & 15);
      float bb = bias[mm][col];
#pragma unroll
      for (int r = 0; r < 4; r++) {
        int rr = r0 + (lane >> 4) * 4 + r;
        int nd = n0 + rr;
        if (nd < NN) outp[mm][(size_t)nd * HDIM + col] = f2bf(acc[r] + bb);
      }
    }
  }
}

// ---------------- attention: one wave per node, vectorized gathers, 2-deep pipeline ----
__global__ __launch_bounds__(256) void k_attn(
    const unsigned short* __restrict__ q, const unsigned short* __restrict__ k,
    const unsigned short* __restrict__ v, const float* __restrict__ efeat,
    const int* __restrict__ colArr, const int* __restrict__ eids,
    const int* __restrict__ starts,
    const float* __restrict__ Wcomb, const float* __restrict__ bcomb,
    unsigned short* __restrict__ out) {
  int t = threadIdx.x;
  int wave = t >> 6, lane = t & 63;
  int node = blockIdx.x * 4 + wave;
  if (node >= NN) return;
  int g = lane >> 4, d = lane & 15;
  int hh = d >> 1;                      // head owned by this lane

  // per-lane q slice (scale folded in)
  float qf[8];
  {
    ushort8 q8 = *(const ushort8*)(q + (size_t)node * HDIM + d * 8);
#pragma unroll
    for (int j = 0; j < 8; j++) qf[j] = bf2f(q8[j]) * 0.25f;
  }
  float wc0 = Wcomb[0 * HH + hh], wc1 = Wcomb[1 * HH + hh];
  float wc2 = Wcomb[2 * HH + hh], wc3 = Wcomb[3 * HH + hh];
  float bc = bcomb[hh];

  int s0 = starts[node], s1 = starts[node + 1];
  float acc[8];
#pragma unroll
  for (int j = 0; j < 8; j++) acc[j] = 0.f;
  float lsum = 0.f;

  // pipeline prologue: ids for chunk0 and chunk1, data for chunk0
  int i0 = s0 + g;
  int e0 = (i0 < s1) ? eids[i0] : -1;
  int c0 = (e0 >= 0) ? colArr[e0] : 0;
  int i1 = s0 + 4 + g;
  int e1 = (i1 < s1) ? eids[i1] : -1;
  int c1 = (e1 >= 0) ? colArr[e1] : 0;
  ushort8 k8 = *(const ushort8*)(k + (size_t)c0 * HDIM + d * 8);
  ushort8 v8 = *(const ushort8*)(v + (size_t)c0 * HDIM + d * 8);
  float4 ef = (e0 >= 0) ? *(const float4*)(efeat + (size_t)e0 * EDI)
                        : float4{0.f, 0.f, 0.f, 0.f};

  for (int base = s0; base < s1; base += 4) {
    // issue next chunk's heavy gathers (addresses already known)
    int cn = c1;
    ushort8 k8n = *(const ushort8*)(k + (size_t)cn * HDIM + d * 8);
    ushort8 v8n = *(const ushort8*)(v + (size_t)cn * HDIM + d * 8);
    float4 efn = (e1 >= 0) ? *(const float4*)(efeat + (size_t)e1 * EDI)
                           : float4{0.f, 0.f, 0.f, 0.f};
    // issue ids for chunk i+2
    int i2 = base + 8 + g;
    int e2 = (i2 < s1) ? eids[i2] : -1;
    int c2 = (e2 >= 0) ? colArr[e2] : 0;

    // compute with current chunk
    bool valid = (e0 >= 0);
    float part = 0.f;
#pragma unroll
    for (int j = 0; j < 8; j++) part += qf[j] * bf2f(k8[j]);
    part += __shfl_xor(part, 1);        // head sum (lanes 2h,2h+1)
    float eb = bc + ef.x * wc0 + ef.y * wc1 + ef.z * wc2 + ef.w * wc3;
    float ex = valid ? __expf(part + eb) : 0.f;
    lsum += ex;
#pragma unroll
    for (int j = 0; j < 8; j++) acc[j] += ex * bf2f(v8[j]);

    // rotate pipeline
    e0 = e1; c0 = c1; k8 = k8n; v8 = v8n; ef = efn;
    e1 = e2; c1 = c2;
  }

  // cross-group reduction (4 groups at lane stride 16)
#pragma unroll
  for (int j = 0; j < 8; j++) {
    acc[j] += __shfl_xor(acc[j], 16);
    acc[j] += __shfl_xor(acc[j], 32);
  }
  lsum += __shfl_xor(lsum, 16);
  lsum += __shfl_xor(lsum, 32);

  if (g == 0) {
    float inv = 1.f / (lsum + 1e-10f);
    ushort8 o;
#pragma unroll
    for (int j = 0; j < 8; j++) o[j] = f2bf(acc[j] * inv);
    *(ushort8*)(out + (size_t)node * HDIM + d * 8) = o;
  }
}

// ---------------- out-projection + residual via MFMA ----------------
__global__ __launch_bounds__(256) void k_oproj_mfma(
    const unsigned short* __restrict__ ao, const unsigned short* __restrict__ Wof,
    const float* __restrict__ bo, float* __restrict__ x) {
  __shared__ unsigned short aos[64][136];
  int t = threadIdx.x;
  int n0 = blockIdx.x * 64;
#pragma unroll
  for (int c = 0; c < 4; c++) {
    int elem = c * 2048 + t * 8;
    int row = elem >> 7, col = elem & 127;
    int nd = n0 + row;
    ushort8 u = {0, 0, 0, 0, 0, 0, 0, 0};
    if (nd < NN) u = *(const ushort8*)(ao + (size_t)nd * HDIM + col);
    *(ushort8*)&aos[row][col] = u;
  }
  __syncthreads();
  int w = t >> 6, lane = t & 63;
  int r0 = w * 16;
  short8 a[4];
#pragma unroll
  for (int kc = 0; kc < 4; kc++)
    a[kc] = *(const short8*)&aos[r0 + (lane & 15)][kc * 32 + (lane >> 4) * 8];
  for (int ct = 0; ct < 8; ct++) {
    floatx4 acc = {0.f, 0.f, 0.f, 0.f};
#pragma unroll
    for (int kc = 0; kc < 4; kc++) {
      short8 b = *(const short8*)(Wof + ((size_t)(ct * 4 + kc) * 64 + lane) * 8);
      acc = __builtin_amdgcn_mfma_f32_16x16x32_bf16(a[kc], b, acc, 0, 0, 0);
    }
    int col = ct * 16 + (lane & 15);
    float bb = bo[col];
#pragma unroll
    for (int r = 0; r < 4; r++) {
      int rr = r0 + (lane >> 4) * 4 + r;
      int nd = n0 + rr;
      if (nd < NN) {
        size_t idx = (size_t)nd * HDIM + col;
        x[idx] = x[idx] + acc[r] + bb;
      }
    }
  }
}

// ---------------- LN2 + FFN + residual via MFMA: 32 nodes/block ----------------
__global__ __launch_bounds__(256) void k_ffn_mfma(
    const float* __restrict__ xin,
    const unsigned short* __restrict__ W1f, const float* __restrict__ b1,
    const unsigned short* __restrict__ W2f, const float* __restrict__ b2,
    const float* __restrict__ g, const float* __restrict__ be,
    float* __restrict__ x) {
  __shared__ unsigned short xn[32][136];
  __shared__ unsigned short hs[32][520];
  int t = threadIdx.x;
  int n0 = blockIdx.x * 32;
  {
    int row = t >> 3, oct = t & 7;   // 8 lanes/row, 16 elems each
    int node = n0 + row;
    float xv[16];
    float s = 0.f, sq = 0.f;
    if (node < NN) {
      const float* xr = xin + (size_t)node * HDIM + oct * 16;
#pragma unroll
      for (int c = 0; c < 4; c++) {
        float4 f = *(const float4*)(xr + c * 4);
        xv[c*4+0]=f.x; xv[c*4+1]=f.y; xv[c*4+2]=f.z; xv[c*4+3]=f.w;
      }
#pragma unroll
      for (int j = 0; j < 16; j++) { s += xv[j]; sq += xv[j]*xv[j]; }
    } else {
#pragma unroll
      for (int j = 0; j < 16; j++) xv[j] = 0.f;
    }
    s += __shfl_xor(s, 1); s += __shfl_xor(s, 2); s += __shfl_xor(s, 4);
    sq += __shfl_xor(sq, 1); sq += __shfl_xor(sq, 2); sq += __shfl_xor(sq, 4);
    float m = s * (1.f / HDIM);
    float rv = rsqrtf(sq * (1.f / HDIM) - m * m + 1e-5f);
#pragma unroll
    for (int cb = 0; cb < 2; cb++) {
      ushort8 u;
#pragma unroll
      for (int j = 0; j < 8; j++) {
        int col = oct * 16 + cb * 8 + j;
        u[j] = f2bf((xv[cb*8+j] - m) * rv * g[col] + be[col]);
      }
      *(ushort8*)&xn[row][oct * 16 + cb * 8] = u;
    }
  }
  __syncthreads();
  int w = t >> 6, lane = t & 63;
  int rt = w & 1, r0 = rt * 16;
  int cthalf = w >> 1;
  short8 a[4];
#pragma unroll
  for (int kc = 0; kc < 4; kc++)
    a[kc] = *(const short8*)&xn[r0 + (lane & 15)][kc * 32 + (lane >> 4) * 8];
  // GEMM1: hidden = relu(xn @ W1 + b1), bf16 into LDS
  for (int ci = 0; ci < 16; ci++) {
    int ct = cthalf * 16 + ci;
    floatx4 acc = {0.f, 0.f, 0.f, 0.f};
#pragma unroll
    for (int kc = 0; kc < 4; kc++) {
      short8 b = *(const short8*)(W1f + ((size_t)(ct * 4 + kc) * 64 + lane) * 8);
      acc = __builtin_amdgcn_mfma_f32_16x16x32_bf16(a[kc], b, acc, 0, 0, 0);
    }
    int col = ct * 16 + (lane & 15);
    float bb = b1[col];
#pragma unroll
    for (int r = 0; r < 4; r++) {
      int rr = r0 + (lane >> 4) * 4 + r;
      hs[rr][col] = f2bf(fmaxf(acc[r] + bb, 0.f));
    }
  }
  __syncthreads();
  // GEMM2: out = hidden @ W2 + b2 + xin
  short8 ah[16];
#pragma unroll
  for (int kc = 0; kc < 16; kc++)
    ah[kc] = *(const short8*)&hs[r0 + (lane & 15)][kc * 32 + (lane >> 4) * 8];
  for (int ci = 0; ci < 4; ci++) {
    int ct = cthalf * 4 + ci;
    floatx4 acc = {0.f, 0.f, 0.f, 0.f};
#pragma unroll
    for (int kc = 0; kc < 16; kc++) {
      short8 b = *(const short8*)(W2f + ((size_t)(ct * 16 + kc) * 64 + lane) * 8);
      acc = __builtin_amdgcn_mfma_f32_16x16x32_bf16(ah[kc], b, acc, 0, 0, 0);
    }
    int col = ct * 16 + (lane & 15);
    float bb = b2[col];
#pragma unroll
    for (int r = 0; r < 4; r++) {
      int rr = r0 + (lane >> 4) * 4 + r;
      int nd = n0 + rr;
      if (nd < NN) {
        size_t idx = (size_t)nd * HDIM + col;
        x[idx] = xin[idx] + acc[r] + bb;
      }
    }
  }
}

// ---------------- final LN -> d_out ----------------
__global__ void k_final(const float* __restrict__ x, const float* __restrict__ g,
                        const float* __restrict__ be, float* __restrict__ outx) {
  __shared__ float xs[16][HDIM + 1];
  __shared__ float mv[16][2];
  int t = threadIdx.x;  // 128
  int n0 = blockIdx.x * 16;
  for (int nb = 0; nb < 16; nb++) {
    int node = n0 + nb;
    xs[nb][t] = (node < NN) ? x[node * HDIM + t] : 0.f;
  }
  __syncthreads();
  if (t < 16) {
    float m = 0.f;
    for (int i = 0; i < HDIM; i++) m += xs[t][i];
    m *= (1.f / HDIM);
    float var = 0.f;
    for (int i = 0; i < HDIM; i++) { float d = xs[t][i] - m; var += d * d; }
    var *= (1.f / HDIM);
    mv[t][0] = m;
    mv[t][1] = rsqrtf(var + 1e-5f);
  }
  __syncthreads();
  float gg = g[t], bb = be[t];
  for (int nb = 0; nb < 16; nb++) {
    int node = n0 + nb;
    if (node < NN) outx[node * HDIM + t] = (xs[nb][t] - mv[nb][0]) * mv[nb][1] * gg + bb;
  }
}

// ---------------- graph mean pooling (batch is sorted; counts from gstart) ----------------
__global__ void k_pool(const float* __restrict__ outx, const int* __restrict__ gstart,
                       float* __restrict__ outg) {
  __shared__ float part[4][HDIM];
  int g = blockIdx.x;
  int t = threadIdx.x;  // 512
  int hd = t & 127, p = t >> 7;
  int s0 = gstart[g];
  int c = gstart[g + 1] - s0;
  float s = 0.f;
  for (int i = p; i < c; i += 4) s += outx[(size_t)(s0 + i) * HDIM + hd];
  part[p][hd] = s;
  __syncthreads();
  if (p == 0) {
    float tot = part[0][hd] + part[1][hd] + part[2][hd] + part[3][hd];
    outg[g * HDIM + hd] = tot / fmaxf((float)c, 1.f);
  }
}

extern "C" void kernel_launch(void* const* d_in, const int* in_sizes, int n_in,
                              void* d_out, int out_size, void* d_ws, size_t ws_size,
                              hipStream_t stream) {
  const float* h      = (const float*)d_in[0];
  const float* e      = (const float*)d_in[1];
  const int*   eidx   = (const int*)d_in[2];
  const int*   batch  = (const int*)d_in[3];
  const float* node_W = (const float*)d_in[4];
  const float* node_b = (const float*)d_in[5];
  const float* edge_W = (const float*)d_in[6];
  const float* edge_b = (const float*)d_in[7];
  const float* Wq  = (const float*)d_in[8];
  const float* bq  = (const float*)d_in[9];
  const float* Wk  = (const float*)d_in[10];
  const float* bk  = (const float*)d_in[11];
  const float* Wv  = (const float*)d_in[12];
  const float* bv  = (const float*)d_in[13];
  const float* Wo  = (const float*)d_in[14];
  const float* bo  = (const float*)d_in[15];
  const float* Web = (const float*)d_in[16];
  const float* beb = (const float*)d_in[17];
  const float* W1  = (const float*)d_in[18];
  const float* b1  = (const float*)d_in[19];
  const float* W2  = (const float*)d_in[20];
  const float* b2  = (const float*)d_in[21];
  const float* g1  = (const float*)d_in[22];
  const float* be1 = (const float*)d_in[23];
  const float* g2  = (const float*)d_in[24];
  const float* be2 = (const float*)d_in[25];
  const float* gF  = (const float*)d_in[26];
  const float* bF  = (const float*)d_in[27];

  const int* rowArr = eidx;
  const int* colArr = eidx + EE;

  char* ws = (char*)d_ws;
  size_t off = 0;
  auto alloc = [&](size_t bytes) -> void* {
    void* p = ws + off;
    off = (off + bytes + 255) & ~(size_t)255;
    return p;
  };
  float* x    = (float*)alloc((size_t)NN * HDIM * 4);
  unsigned short* qb = (unsigned short*)alloc((size_t)NN * HDIM * 2);
  unsigned short* kb = (unsigned short*)alloc((size_t)NN * HDIM * 2);
  unsigned short* vb = (unsigned short*)alloc((size_t)NN * HDIM * 2);
  unsigned short* ao = (unsigned short*)alloc((size_t)NN * HDIM * 2);
  int* deg    = (int*)alloc((size_t)NN * 4);
  int* starts = (int*)alloc((size_t)(NN + 1) * 4);
  int* cursor = (int*)alloc((size_t)NN * 4);
  int* eids   = (int*)alloc((size_t)EE * 4);
  float* Wcomb = (float*)alloc((size_t)LL * EDI * HH * 4);
  float* bcomb = (float*)alloc((size_t)LL * HH * 4);
  int* gstart = (int*)alloc((size_t)(GG + 1) * 4);
  // fragment-packed bf16 weights
  const int QKV_FRAG = 8 * 4 * 512;    // 16384 elems per matrix per layer
  const int FFN_FRAG1 = 32 * 4 * 512;  // 65536
  const int FFN_FRAG2 = 8 * 16 * 512;  // 65536
  unsigned short* Wqf = (unsigned short*)alloc((size_t)LL * QKV_FRAG * 2);
  unsigned short* Wkf = (unsigned short*)alloc((size_t)LL * QKV_FRAG * 2);
  unsigned short* Wvf = (unsigned short*)alloc((size_t)LL * QKV_FRAG * 2);
  unsigned short* Wof = (unsigned short*)alloc((size_t)LL * QKV_FRAG * 2);
  unsigned short* W1f = (unsigned short*)alloc((size_t)LL * FFN_FRAG1 * 2);
  unsigned short* W2f = (unsigned short*)alloc((size_t)LL * FFN_FRAG2 * 2);

  hipMemsetAsync(deg, 0, (size_t)NN * 4, stream);

  k_node_proj<<<(NN + 31) / 32, 128, 0, stream>>>(h, node_W, node_b, x);
  k_wcomb<<<1, 256, 0, stream>>>(edge_W, edge_b, Web, beb, Wcomb, bcomb);
  k_pack<<<(LL * QKV_FRAG + 255) / 256, 256, 0, stream>>>(Wq, Wqf, HDIM, HDIM, LL);
  k_pack<<<(LL * QKV_FRAG + 255) / 256, 256, 0, stream>>>(Wk, Wkf, HDIM, HDIM, LL);
  k_pack<<<(LL * QKV_FRAG + 255) / 256, 256, 0, stream>>>(Wv, Wvf, HDIM, HDIM, LL);
  k_pack<<<(LL * QKV_FRAG + 255) / 256, 256, 0, stream>>>(Wo, Wof, HDIM, HDIM, LL);
  k_pack<<<(LL * FFN_FRAG1 + 255) / 256, 256, 0, stream>>>(W1, W1f, HDIM, FFD, LL);
  k_pack<<<(LL * FFN_FRAG2 + 255) / 256, 256, 0, stream>>>(W2, W2f, FFD, HDIM, LL);
  k_deg<<<(EE + 255) / 256, 256, 0, stream>>>(rowArr, deg);
  k_scan<<<1, 1024, 0, stream>>>(deg, starts, cursor, NN);
  k_scatter<<<(EE + 255) / 256, 256, 0, stream>>>(rowArr, cursor, eids);
  k_gbounds<<<(NN + 255) / 256, 256, 0, stream>>>(batch, gstart);

  int nb64 = (NN + 63) / 64;
  int nb32 = (NN + 31) / 32;
  for (int l = 0; l < LL; l++) {
    k_ln_qkv_mfma<<<nb64, 256, 0, stream>>>(x,
        Wqf + (size_t)l * QKV_FRAG, bq + (size_t)l * HDIM,
        Wkf + (size_t)l * QKV_FRAG, bk + (size_t)l * HDIM,
        Wvf + (size_t)l * QKV_FRAG, bv + (size_t)l * HDIM,
        g1 + (size_t)l * HDIM, be1 + (size_t)l * HDIM, qb, kb, vb);
    k_attn<<<(NN + 3) / 4, 256, 0, stream>>>(qb, kb, vb, e, colArr, eids, starts,
        Wcomb + (size_t)l * EDI * HH, bcomb + (size_t)l * HH, ao);
    k_oproj_mfma<<<nb64, 256, 0, stream>>>(ao, Wof + (size_t)l * QKV_FRAG,
        bo + (size_t)l * HDIM, x);
    k_ffn_mfma<<<nb32, 256, 0, stream>>>(x,
        W1f + (size_t)l * FFN_FRAG1, b1 + (size_t)l * FFD,
        W2f + (size_t)l * FFN_FRAG2, b2 + (size_t)l * HDIM,
        g2 + (size_t)l * HDIM, be2 + (size_t)l * HDIM, x);
  }

  float* outx = (float*)d_out;
  float* outg = outx + (size_t)NN * HDIM;
  int nblk16 = (NN + 15) / 16;
  k_final<<<nblk16, 128, 0, stream>>>(x, gF, bF, outx);
  k_pool<<<GG, 512, 0, stream>>>(outx, gstart, outg);
}